// Round 6
// baseline (430.783 us; speedup 1.0000x reference)
//
#include <hip/hip_runtime.h>
#include <math.h>

#define Dd 256
#define Nn 4096
#define Bb 4
#define BQ 128      // q rows per attn block (8 waves x 16 in S phase)
#define BK 128      // kv rows per tile
#define SPLIT 2     // KV splits -> grid exactly 256 blocks = 1 round

typedef _Float16 f16;
typedef _Float16 half8 __attribute__((ext_vector_type(8)));
typedef _Float16 half4 __attribute__((ext_vector_type(4)));
typedef float f32x4 __attribute__((ext_vector_type(4)));

#define LOG2E 1.4426950408889634f

// DPP row_ror butterfly over 16-lane rows (VALU pipe, not LDS)
template <int CTRL>
__device__ __forceinline__ float dppf(float x) {
    int r = __builtin_amdgcn_update_dpp(0, __builtin_bit_cast(int, x),
                                        CTRL, 0xF, 0xF, false);
    return __builtin_bit_cast(float, r);
}
__device__ __forceinline__ float red16_max(float x) {
    x = fmaxf(x, dppf<0x128>(x));
    x = fmaxf(x, dppf<0x124>(x));
    x = fmaxf(x, dppf<0x122>(x));
    x = fmaxf(x, dppf<0x121>(x));
    return x;
}
__device__ __forceinline__ float red16_sum(float x) {
    x += dppf<0x128>(x); x += dppf<0x124>(x);
    x += dppf<0x122>(x); x += dppf<0x121>(x);
    return x;
}

// ---------------------------------------------------------------------------
// Kernel 0: W transpose+cast.  Wt[which][d'][d] = (f16) W[d][d']
// ---------------------------------------------------------------------------
__global__ __launch_bounds__(256) void wtrans(
    const float* __restrict__ Wq, const float* __restrict__ Wk,
    const float* __restrict__ Wv, f16* __restrict__ Wt)
{
    __shared__ float ld[64][65];
    const int which = blockIdx.y;
    const float* W = which == 0 ? Wq : (which == 1 ? Wk : Wv);
    const int tr = (blockIdx.x >> 2) * 64;
    const int tc = (blockIdx.x & 3) * 64;
    const int t = threadIdx.x;
    #pragma unroll
    for (int i = 0; i < 16; ++i) {
        int u = t + i * 256, r = u >> 6, c = u & 63;
        ld[r][c] = W[(size_t)(tr + r) * Dd + tc + c];
    }
    __syncthreads();
    f16* Wo = Wt + (size_t)which * Dd * Dd;
    #pragma unroll
    for (int i = 0; i < 16; ++i) {
        int u = t + i * 256, cp = u >> 6, rp = u & 63;
        Wo[(size_t)(tc + cp) * Dd + tr + rp] = (f16)ld[rp][cp];
    }
}

// ---------------------------------------------------------------------------
// Kernel 1: QKV projection (unchanged from R5): W in registers, 1 barrier,
// 256-thread blocks, 2 blocks/CU.
// ---------------------------------------------------------------------------
__global__ __launch_bounds__(256) void qkv_fused(
    const float* __restrict__ x, const f16* __restrict__ Wt,
    const float* __restrict__ bq, const float* __restrict__ bk,
    const float* __restrict__ bv,
    f16* __restrict__ Qh, f16* __restrict__ Kh, f16* __restrict__ Vth)
{
    __shared__ __align__(16) f16 xT[64][264];   // 33792 B

    const int t = threadIdx.x;
    const int wave = t >> 6, lane = t & 63, quad = lane >> 4, l15 = lane & 15;
    const int n0  = blockIdx.x * 64;
    const int ch  = blockIdx.y;           // col half: [128*ch, 128*ch+128)
    const int b   = blockIdx.z;
    const int col0 = ch * 128 + wave * 32;  // this wave's 32 out-cols

    // Stage xT[n][d] = (f16) x[b][d][n0+n]; 256 threads x 16 float4 reads
    const float* xb = x + (size_t)b * Dd * Nn;
    #pragma unroll
    for (int i = 0; i < 16; ++i) {
        int u = t + i * 256, d = u >> 4, nq = (u & 15) * 4;
        float4 v4 = *(const float4*)&xb[(size_t)d * Nn + n0 + nq];
        xT[nq + 0][d] = (f16)v4.x; xT[nq + 1][d] = (f16)v4.y;
        xT[nq + 2][d] = (f16)v4.z; xT[nq + 3][d] = (f16)v4.w;
    }

    // Biases for this wave's two col-tiles (direct, no LDS)
    float bias[3][2];
    #pragma unroll
    for (int ct = 0; ct < 2; ++ct) {
        int col = col0 + ct * 16 + l15;
        bias[0][ct] = bq[col]; bias[1][ct] = bk[col]; bias[2][ct] = bv[col];
    }

    __syncthreads();   // the ONLY barrier: xT visible, read-only hereafter

    #pragma unroll
    for (int which = 0; which < 3; ++which) {
        // B-fragments from L2: 16 x b128 per wave, register-resident
        const f16* Wb = Wt + (size_t)which * Dd * Dd;
        half8 wf[2][8];
        #pragma unroll
        for (int ct = 0; ct < 2; ++ct)
            #pragma unroll
            for (int c = 0; c < 8; ++c)
                wf[ct][c] = *(const half8*)(Wb
                    + (size_t)(col0 + ct * 16 + l15) * Dd + c * 32 + quad * 8);

        // 64 rows x 32 cols per wave: 4 row-groups x 2 col-tiles x 8 chunks
        f32x4 acc[4][2];
        #pragma unroll
        for (int rg = 0; rg < 4; ++rg) {
            acc[rg][0] = (f32x4){0.f, 0.f, 0.f, 0.f};
            acc[rg][1] = (f32x4){0.f, 0.f, 0.f, 0.f};
        }
        #pragma unroll
        for (int rg = 0; rg < 4; ++rg) {
            #pragma unroll
            for (int c = 0; c < 8; ++c) {
                half8 a = *(const half8*)&xT[rg * 16 + l15][c * 32 + quad * 8];
                acc[rg][0] = __builtin_amdgcn_mfma_f32_16x16x32_f16(
                    a, wf[0][c], acc[rg][0], 0, 0, 0);
                acc[rg][1] = __builtin_amdgcn_mfma_f32_16x16x32_f16(
                    a, wf[1][c], acc[rg][1], 0, 0, 0);
            }
        }

        // Epilogue
        if (which < 2) {
            f16* O = (which == 0 ? Qh : Kh) + ((size_t)b * Nn + n0) * Dd;
            #pragma unroll
            for (int rg = 0; rg < 4; ++rg) {
                #pragma unroll
                for (int ct = 0; ct < 2; ++ct) {
                    int col = col0 + ct * 16 + l15;
                    float bvv = bias[which][ct];
                    #pragma unroll
                    for (int r = 0; r < 4; ++r)
                        O[(size_t)(rg * 16 + quad * 4 + r) * Dd + col] =
                            (f16)(acc[rg][ct][r] + bvv);
                }
            }
        } else {
            f16* O = Vth + (size_t)b * Dd * Nn;
            #pragma unroll
            for (int rg = 0; rg < 4; ++rg) {
                #pragma unroll
                for (int ct = 0; ct < 2; ++ct) {
                    int col = col0 + ct * 16 + l15;
                    float bvv = bias[2][ct];
                    half4 o;
                    #pragma unroll
                    for (int r = 0; r < 4; ++r) o[r] = (f16)(acc[rg][ct][r] + bvv);
                    *(half4*)&O[(size_t)col * Nn + n0 + rg * 16 + quad * 4] = o;
                }
            }
        }
    }
}

// ---------------------------------------------------------------------------
// Kernel 2: MFMA flash attention, R19 = R4 structure + T15 double-pipeline:
// PV runs ONE TILE BEHIND. Per tile k: issue S(k) MFMAs -> rescale with
// alpha(k-1) (VALU, overlaps S) -> PV(k-1) MFMAs -> softmax(k) VALU
// (overlaps PV execution: separate pipes, in-order issue, non-blocking).
// Barriers drop 3 -> 2 per tile. Buffers: Ps(k) aliases Ks[k&1] (K(k) dead
// after S(k)); write-late K(k+1) targets Ks[(k+1)&1] which held Ps(k-1) --
// dead after PV(k-1) this iteration, protected by the mid-tile barrier.
// V double-buffered in regs (vA/vB, alternated at COMPILE TIME: unroll-2).
// ---------------------------------------------------------------------------
template <bool FIRST>
__device__ __forceinline__ void tile_step(
    int k0, bool havenext,
    const f16* __restrict__ Kb, const f16* __restrict__ Vrow,
    const half8 (&qf)[8],
    half8 (&vW)[2][4], half8 (&vR)[2][4],
    f32x4 (&acc)[16], f32x4& m4, f32x4& l4,
    f16 (*KsCur)[264], f16 (*KsOth)[264],
    float (*alpha_sp)[16],
    int t, int wave, int quad, int l15)
{
    const int kn = k0 + BK;
    const int pr = quad * 4;

    // 1. Issue-early: next K tile -> regs (consumed by ds_write at step 7)
    half8 kreg[8];
    if (havenext) {
        #pragma unroll
        for (int i = 0; i < 8; ++i) {
            int u = t + i * 512;
            int r = u >> 5, c = u & 31;
            kreg[i] = *(const half8*)(Kb + (size_t)(kn + r) * Dd + c * 8);
        }
    }
    // 2. V(k) -> vW. First consumed by PV at the NEXT tile step: a full
    //    iteration of latency slack.
    #pragma unroll
    for (int dt = 0; dt < 2; ++dt)
        #pragma unroll
        for (int cbb = 0; cbb < 4; ++cbb)
            vW[dt][cbb] = *(const half8*)(Vrow + (size_t)dt * 16 * Nn + k0 + cbb * 32);

    // 3. S = Q K^T (log2 domain) from KsCur
    f32x4 S[8];
    #pragma unroll
    for (int cb = 0; cb < 8; ++cb) S[cb] = (f32x4){0.f, 0.f, 0.f, 0.f};
    #pragma unroll
    for (int c = 0; c < 8; ++c) {
        #pragma unroll
        for (int cb = 0; cb < 8; ++cb) {
            half8 kb = *(const half8*)&KsCur[cb * 16 + l15][c * 32 + quad * 8];
            S[cb] = __builtin_amdgcn_mfma_f32_16x16x32_f16(qf[c], kb, S[cb], 0, 0, 0);
        }
    }

    // 4. Rescale acc by alpha(k-1) (LDS read + VALU; overlaps S execution)
    //    then PV(k-1): MFMAs from Ps(k-1) alias of KsOth with vR.
    if (!FIRST) {
        f16 (*Pp)[16][136] = (f16 (*)[16][136])&KsOth[0][0];
        float4 alq[8];
        int need = 0;
        #pragma unroll
        for (int qb = 0; qb < 8; ++qb) {
            alq[qb] = *(const float4*)&alpha_sp[qb][pr];
            need |= (alq[qb].x != 1.f) | (alq[qb].y != 1.f) |
                    (alq[qb].z != 1.f) | (alq[qb].w != 1.f);
        }
        if (__any(need)) {
            #pragma unroll
            for (int qb = 0; qb < 8; ++qb) {
                f32x4 a = {alq[qb].x, alq[qb].y, alq[qb].z, alq[qb].w};
                acc[qb * 2 + 0] *= a;
                acc[qb * 2 + 1] *= a;
            }
        }
        #pragma unroll
        for (int qb = 0; qb < 8; ++qb) {
            #pragma unroll
            for (int cbb = 0; cbb < 4; ++cbb) {
                half8 ap = *(const half8*)&Pp[qb][l15][cbb * 32 + quad * 8];
                acc[qb * 2 + 0] = __builtin_amdgcn_mfma_f32_16x16x32_f16(
                    ap, vR[0][cbb], acc[qb * 2 + 0], 0, 0, 0);
                acc[qb * 2 + 1] = __builtin_amdgcn_mfma_f32_16x16x32_f16(
                    ap, vR[1][cbb], acc[qb * 2 + 1], 0, 0, 0);
            }
        }
    }

    // 5. Online softmax (exp2 domain) -- VALU/trans work that overlaps the
    //    PV(k-1) MFMAs still executing on the matrix pipe.
    f32x4 tmax = S[0];
    #pragma unroll
    for (int cb = 1; cb < 8; ++cb) {
        tmax.x = fmaxf(tmax.x, S[cb].x); tmax.y = fmaxf(tmax.y, S[cb].y);
        tmax.z = fmaxf(tmax.z, S[cb].z); tmax.w = fmaxf(tmax.w, S[cb].w);
    }
    tmax.x = red16_max(tmax.x); tmax.y = red16_max(tmax.y);
    tmax.z = red16_max(tmax.z); tmax.w = red16_max(tmax.w);
    f32x4 newm;
    newm.x = fmaxf(m4.x, tmax.x); newm.y = fmaxf(m4.y, tmax.y);
    newm.z = fmaxf(m4.z, tmax.z); newm.w = fmaxf(m4.w, tmax.w);
    f32x4 al;
    al.x = __builtin_amdgcn_exp2f(m4.x - newm.x);
    al.y = __builtin_amdgcn_exp2f(m4.y - newm.y);
    al.z = __builtin_amdgcn_exp2f(m4.z - newm.z);
    al.w = __builtin_amdgcn_exp2f(m4.w - newm.w);
    #pragma unroll
    for (int cb = 0; cb < 8; ++cb) {       // P overwrites S (reg saver)
        S[cb].x = __builtin_amdgcn_exp2f(S[cb].x - newm.x);
        S[cb].y = __builtin_amdgcn_exp2f(S[cb].y - newm.y);
        S[cb].z = __builtin_amdgcn_exp2f(S[cb].z - newm.z);
        S[cb].w = __builtin_amdgcn_exp2f(S[cb].w - newm.w);
    }
    f32x4 rsum = S[0];
    #pragma unroll
    for (int cb = 1; cb < 8; ++cb) rsum += S[cb];
    rsum.x = red16_sum(rsum.x); rsum.y = red16_sum(rsum.y);
    rsum.z = red16_sum(rsum.z); rsum.w = red16_sum(rsum.w);
    l4 = l4 * al + rsum;
    m4 = newm;

    // 6. Barrier: every wave done reading KsCur (S), KsOth (PV prev) and
    //    last tile's alpha_s.
    __syncthreads();

    // 7. Publish P(k) -> alias of KsCur; alpha(k) -> alpha_s;
    //    write-late K(k+1) -> KsOth (overwrites dead Ps(k-1)).
    f16 (*Ps)[16][136] = (f16 (*)[16][136])&KsCur[0][0];
    #pragma unroll
    for (int cb = 0; cb < 8; ++cb) {
        Ps[wave][pr + 0][cb * 16 + l15] = (f16)S[cb].x;
        Ps[wave][pr + 1][cb * 16 + l15] = (f16)S[cb].y;
        Ps[wave][pr + 2][cb * 16 + l15] = (f16)S[cb].z;
        Ps[wave][pr + 3][cb * 16 + l15] = (f16)S[cb].w;
    }
    if (l15 == 0) {
        float4 a4 = {al.x, al.y, al.z, al.w};
        *(float4*)&alpha_sp[wave][pr] = a4;
    }
    if (havenext) {
        #pragma unroll
        for (int i = 0; i < 8; ++i) {
            int u = t + i * 512;
            int r = u >> 5, c = u & 31;
            *(half8*)&KsOth[r][c * 8] = kreg[i];
        }
    }
    __syncthreads();   // P(k)/alpha(k)/K(k+1) visible for next tile
}

__global__ __launch_bounds__(512, 2) void attn_mfma(
    const f16* __restrict__ Qh, const f16* __restrict__ Kh,
    const f16* __restrict__ Vth, f16* __restrict__ Opart,
    float* __restrict__ mpart, float* __restrict__ lpart)
{
    __shared__ __align__(16) f16 Ks[2][BK][264];  // 135168 B, double-buffered
    __shared__ float alpha_s[8][16];              //   512 B
    __shared__ float l_sh[8][16];                 //   512 B

    const int t    = threadIdx.x;
    const int wave = t >> 6, lane = t & 63;
    const int quad = lane >> 4, l15 = lane & 15;
    const int b    = blockIdx.y;
    const int s    = blockIdx.z;
    const int q0   = blockIdx.x * BQ;
    const int qw   = q0 + wave * 16;       // this wave's S-phase q rows
    const int kvlen = Nn / SPLIT;          // 2048 -> 16 tiles
    const int kv0  = s * kvlen;

    // Q A-fragments, pre-scaled by log2(e)
    half8 qf[8];
    const f16* Qrow = Qh + ((size_t)b * Nn + qw + l15) * Dd + quad * 8;
    #pragma unroll
    for (int c = 0; c < 8; ++c) {
        qf[c] = *(const half8*)(Qrow + c * 32);
        qf[c] = qf[c] * (f16)LOG2E;
    }

    // acc[qb*2+dt]: q-block qb (0..7), d-cols 32*wave + dt*16 + l15 (dt 0..1)
    f32x4 acc[16];
    #pragma unroll
    for (int n = 0; n < 16; ++n) acc[n] = (f32x4){0.f, 0.f, 0.f, 0.f};
    f32x4 m4 = {-1e30f, -1e30f, -1e30f, -1e30f};
    f32x4 l4 = {0.f, 0.f, 0.f, 0.f};

    const f16* Kb   = Kh + (size_t)b * Nn * Dd;
    const f16* Vrow = Vth + (size_t)b * Dd * Nn
                    + (size_t)(wave * 32 + l15) * Nn + quad * 8;

    // Prologue: stage first K tile into Ks[0]
    #pragma unroll
    for (int i = 0; i < 8; ++i) {
        int u = t + i * 512;
        int r = u >> 5, c = u & 31;
        *(half8*)&Ks[0][r][c * 8] =
            *(const half8*)(Kb + (size_t)(kv0 + r) * Dd + c * 8);
    }
    __syncthreads();

    half8 vA[2][4], vB[2][4];
    f16 (*Ks0)[264] = Ks[0];
    f16 (*Ks1)[264] = Ks[1];

    // 16 tiles as 8 unroll-2 pairs (compile-time vA/vB + buffer alternation)
    for (int p = 0; p < 16; p += 2) {
        int k0 = kv0 + p * BK;
        if (p == 0)
            tile_step<true >(k0, true, Kb, Vrow, qf, vA, vB, acc, m4, l4,
                             Ks0, Ks1, alpha_s, t, wave, quad, l15);
        else
            tile_step<false>(k0, true, Kb, Vrow, qf, vA, vB, acc, m4, l4,
                             Ks0, Ks1, alpha_s, t, wave, quad, l15);
        tile_step<false>(k0 + BK, p + 2 < 16, Kb, Vrow, qf, vB, vA, acc, m4, l4,
                         Ks1, Ks0, alpha_s, t, wave, quad, l15);
    }

    // Tail: PV(15). alpha(15) published + barrier'd; Ps(15) in Ks[1] (tile
    // 15 is odd); V(15) in vB.
    {
        const int pr = quad * 4;
        f16 (*Pp)[16][136] = (f16 (*)[16][136])&Ks1[0][0];
        float4 alq[8];
        int need = 0;
        #pragma unroll
        for (int qb = 0; qb < 8; ++qb) {
            alq[qb] = *(const float4*)&alpha_s[qb][pr];
            need |= (alq[qb].x != 1.f) | (alq[qb].y != 1.f) |
                    (alq[qb].z != 1.f) | (alq[qb].w != 1.f);
        }
        if (__any(need)) {
            #pragma unroll
            for (int qb = 0; qb < 8; ++qb) {
                f32x4 a = {alq[qb].x, alq[qb].y, alq[qb].z, alq[qb].w};
                acc[qb * 2 + 0] *= a;
                acc[qb * 2 + 1] *= a;
            }
        }
        #pragma unroll
        for (int qb = 0; qb < 8; ++qb) {
            #pragma unroll
            for (int cbb = 0; cbb < 4; ++cbb) {
                half8 ap = *(const half8*)&Pp[qb][l15][cbb * 32 + quad * 8];
                acc[qb * 2 + 0] = __builtin_amdgcn_mfma_f32_16x16x32_f16(
                    ap, vB[0][cbb], acc[qb * 2 + 0], 0, 0, 0);
                acc[qb * 2 + 1] = __builtin_amdgcn_mfma_f32_16x16x32_f16(
                    ap, vB[1][cbb], acc[qb * 2 + 1], 0, 0, 0);
            }
        }
    }

    // Publish l, write m/l partials (this wave's own 16 q rows)
    if (l15 == 0) {
        const int pr = quad * 4;
        float4 lv = {l4.x, l4.y, l4.z, l4.w};
        *(float4*)&l_sh[wave][pr] = lv;
        float mv[4] = {m4.x, m4.y, m4.z, m4.w};
        float lvv[4] = {l4.x, l4.y, l4.z, l4.w};
        #pragma unroll
        for (int r = 0; r < 4; ++r) {
            int n = qw + pr + r;
            mpart[(size_t)(s * Bb + b) * Nn + n] = mv[r];
            lpart[(size_t)(s * Bb + b) * Nn + n] = lvv[r];
        }
    }
    __syncthreads();

    // Normalize + store partial O: 8 q-blocks x this wave's 2 d-tiles
    f16* Ob = Opart + (size_t)(s * Bb + b) * Dd * Nn;
    #pragma unroll
    for (int qb = 0; qb < 8; ++qb) {
        float4 lq = *(const float4*)&l_sh[qb][quad * 4];
        f32x4 inv = {1.f / lq.x, 1.f / lq.y, 1.f / lq.z, 1.f / lq.w};
        #pragma unroll
        for (int dt = 0; dt < 2; ++dt) {
            int d = wave * 32 + dt * 16 + l15;
            f32x4 o = acc[qb * 2 + dt] * inv;
            half4 oh;
            oh[0] = (f16)o.x; oh[1] = (f16)o.y; oh[2] = (f16)o.z; oh[3] = (f16)o.w;
            *(half4*)&Ob[(size_t)d * Nn + q0 + qb * 16 + quad * 4] = oh;
        }
    }
}

// ---------------------------------------------------------------------------
// Kernel 3: combine split partials (exp2 domain).
// ---------------------------------------------------------------------------
__global__ __launch_bounds__(256) void combine(
    const f16* __restrict__ Opart, const float* __restrict__ mpart,
    const float* __restrict__ lpart, float* __restrict__ out)
{
    const int t = threadIdx.x;
    const int n0 = (blockIdx.x * 256 + t) * 8;
    const int d = blockIdx.y, b = blockIdx.z;

    float m[SPLIT][8], l[SPLIT][8];
    #pragma unroll
    for (int s = 0; s < SPLIT; ++s) {
        size_t base = (size_t)(s * Bb + b) * Nn + n0;
        float4 a0 = *(const float4*)&mpart[base];
        float4 a1 = *(const float4*)&mpart[base + 4];
        float4 c0 = *(const float4*)&lpart[base];
        float4 c1 = *(const float4*)&lpart[base + 4];
        m[s][0]=a0.x; m[s][1]=a0.y; m[s][2]=a0.z; m[s][3]=a0.w;
        m[s][4]=a1.x; m[s][5]=a1.y; m[s][6]=a1.z; m[s][7]=a1.w;
        l[s][0]=c0.x; l[s][1]=c0.y; l[s][2]=c0.z; l[s][3]=c0.w;
        l[s][4]=c1.x; l[s][5]=c1.y; l[s][6]=c1.z; l[s][7]=c1.w;
    }
    float w[SPLIT][8];
    #pragma unroll
    for (int jx = 0; jx < 8; ++jx) {
        float M = m[0][jx];
        #pragma unroll
        for (int s = 1; s < SPLIT; ++s) M = fmaxf(M, m[s][jx]);
        float L = 0.f;
        #pragma unroll
        for (int s = 0; s < SPLIT; ++s) {
            float ws = l[s][jx] * __builtin_amdgcn_exp2f(m[s][jx] - M);
            w[s][jx] = ws; L += ws;
        }
        float invL = 1.f / L;
        #pragma unroll
        for (int s = 0; s < SPLIT; ++s) w[s][jx] *= invL;
    }

    float o[8];
    #pragma unroll
    for (int jx = 0; jx < 8; ++jx) o[jx] = 0.f;
    #pragma unroll
    for (int s = 0; s < SPLIT; ++s) {
        half8 h = *(const half8*)&Opart[((size_t)(s * Bb + b) * Dd + d) * Nn + n0];
        #pragma unroll
        for (int jx = 0; jx < 8; ++jx) o[jx] += w[s][jx] * (float)h[jx];
    }
    float* op = out + ((size_t)b * Dd + d) * Nn + n0;
    f32x4 o0 = {o[0], o[1], o[2], o[3]};
    f32x4 o1 = {o[4], o[5], o[6], o[7]};
    *(f32x4*)op = o0;
    *(f32x4*)(op + 4) = o1;
}

extern "C" void kernel_launch(void* const* d_in, const int* in_sizes, int n_in,
                              void* d_out, int out_size, void* d_ws, size_t ws_size,
                              hipStream_t stream) {
    const float* x  = (const float*)d_in[0];
    const float* Wq = (const float*)d_in[1];
    const float* bq = (const float*)d_in[2];
    const float* Wk = (const float*)d_in[3];
    const float* bk = (const float*)d_in[4];
    const float* Wv = (const float*)d_in[5];
    const float* bv = (const float*)d_in[6];
    float* out = (float*)d_out;

    f16* Qh    = (f16*)d_ws;
    f16* Kh    = Qh + (size_t)Bb * Nn * Dd;
    f16* Vth   = Kh + (size_t)Bb * Nn * Dd;
    f16* Wt    = Vth + (size_t)Bb * Nn * Dd;
    f16* Opart = Wt + (size_t)3 * Dd * Dd;
    float* mpart = (float*)(Opart + (size_t)SPLIT * Bb * Dd * Nn);
    float* lpart = mpart + (size_t)SPLIT * Bb * Nn;

    wtrans<<<dim3(16, 3), 256, 0, stream>>>(Wq, Wk, Wv, Wt);
    qkv_fused<<<dim3(Nn / 64, 2, Bb), 256, 0, stream>>>(
        x, Wt, bq, bk, bv, Qh, Kh, Vth);
    attn_mfma<<<dim3(Nn / BQ, Bb, SPLIT), 512, 0, stream>>>(
        Qh, Kh, Vth, Opart, mpart, lpart);
    combine<<<dim3(Nn / 2048, Dd, Bb), 256, 0, stream>>>(
        Opart, mpart, lpart, out);
}

// Round 7
// 304.677 us; speedup vs baseline: 1.4139x; 1.4139x over previous
//
#include <hip/hip_runtime.h>
#include <math.h>

#define Dd 256
#define Nn 4096
#define Bb 4
#define BQ 128      // q rows per attn block (8 waves x 16 in S phase)
#define BK 128      // kv rows per tile
#define SPLIT 2     // KV splits -> grid exactly 256 blocks = 1 round
#define PSTRIDE 140 // Ps row stride in f16: 70 dwords -> quad bank-starts
                    // {0,24,16,8} disjoint -> publish writes 2-way (free).
                    // 136 (68 dw) put quads {0,2},{1,3} on same octet: 4-way.

typedef _Float16 f16;
typedef _Float16 half8 __attribute__((ext_vector_type(8)));
typedef _Float16 half4 __attribute__((ext_vector_type(4)));
typedef float f32x4 __attribute__((ext_vector_type(4)));

#define LOG2E 1.4426950408889634f

// DPP row_ror butterfly over 16-lane rows (VALU pipe, not LDS)
template <int CTRL>
__device__ __forceinline__ float dppf(float x) {
    int r = __builtin_amdgcn_update_dpp(0, __builtin_bit_cast(int, x),
                                        CTRL, 0xF, 0xF, false);
    return __builtin_bit_cast(float, r);
}
__device__ __forceinline__ float red16_max(float x) {
    x = fmaxf(x, dppf<0x128>(x));
    x = fmaxf(x, dppf<0x124>(x));
    x = fmaxf(x, dppf<0x122>(x));
    x = fmaxf(x, dppf<0x121>(x));
    return x;
}
__device__ __forceinline__ float red16_sum(float x) {
    x += dppf<0x128>(x); x += dppf<0x124>(x);
    x += dppf<0x122>(x); x += dppf<0x121>(x);
    return x;
}

// ---------------------------------------------------------------------------
// Kernel 0: W transpose+cast.  Wt[which][d'][d] = (f16) W[d][d']
// ---------------------------------------------------------------------------
__global__ __launch_bounds__(256) void wtrans(
    const float* __restrict__ Wq, const float* __restrict__ Wk,
    const float* __restrict__ Wv, f16* __restrict__ Wt)
{
    __shared__ float ld[64][65];
    const int which = blockIdx.y;
    const float* W = which == 0 ? Wq : (which == 1 ? Wk : Wv);
    const int tr = (blockIdx.x >> 2) * 64;
    const int tc = (blockIdx.x & 3) * 64;
    const int t = threadIdx.x;
    #pragma unroll
    for (int i = 0; i < 16; ++i) {
        int u = t + i * 256, r = u >> 6, c = u & 63;
        ld[r][c] = W[(size_t)(tr + r) * Dd + tc + c];
    }
    __syncthreads();
    f16* Wo = Wt + (size_t)which * Dd * Dd;
    #pragma unroll
    for (int i = 0; i < 16; ++i) {
        int u = t + i * 256, cp = u >> 6, rp = u & 63;
        Wo[(size_t)(tc + cp) * Dd + tr + rp] = (f16)ld[rp][cp];
    }
}

// ---------------------------------------------------------------------------
// Kernel 1: QKV projection (unchanged from R5): W in registers, 1 barrier,
// 256-thread blocks, 2 blocks/CU.
// ---------------------------------------------------------------------------
__global__ __launch_bounds__(256) void qkv_fused(
    const float* __restrict__ x, const f16* __restrict__ Wt,
    const float* __restrict__ bq, const float* __restrict__ bk,
    const float* __restrict__ bv,
    f16* __restrict__ Qh, f16* __restrict__ Kh, f16* __restrict__ Vth)
{
    __shared__ __align__(16) f16 xT[64][264];   // 33792 B

    const int t = threadIdx.x;
    const int wave = t >> 6, lane = t & 63, quad = lane >> 4, l15 = lane & 15;
    const int n0  = blockIdx.x * 64;
    const int ch  = blockIdx.y;           // col half: [128*ch, 128*ch+128)
    const int b   = blockIdx.z;
    const int col0 = ch * 128 + wave * 32;  // this wave's 32 out-cols

    // Stage xT[n][d] = (f16) x[b][d][n0+n]; 256 threads x 16 float4 reads
    const float* xb = x + (size_t)b * Dd * Nn;
    #pragma unroll
    for (int i = 0; i < 16; ++i) {
        int u = t + i * 256, d = u >> 4, nq = (u & 15) * 4;
        float4 v4 = *(const float4*)&xb[(size_t)d * Nn + n0 + nq];
        xT[nq + 0][d] = (f16)v4.x; xT[nq + 1][d] = (f16)v4.y;
        xT[nq + 2][d] = (f16)v4.z; xT[nq + 3][d] = (f16)v4.w;
    }

    // Biases for this wave's two col-tiles (direct, no LDS)
    float bias[3][2];
    #pragma unroll
    for (int ct = 0; ct < 2; ++ct) {
        int col = col0 + ct * 16 + l15;
        bias[0][ct] = bq[col]; bias[1][ct] = bk[col]; bias[2][ct] = bv[col];
    }

    __syncthreads();   // the ONLY barrier: xT visible, read-only hereafter

    #pragma unroll
    for (int which = 0; which < 3; ++which) {
        // B-fragments from L2: 16 x b128 per wave, register-resident
        const f16* Wb = Wt + (size_t)which * Dd * Dd;
        half8 wf[2][8];
        #pragma unroll
        for (int ct = 0; ct < 2; ++ct)
            #pragma unroll
            for (int c = 0; c < 8; ++c)
                wf[ct][c] = *(const half8*)(Wb
                    + (size_t)(col0 + ct * 16 + l15) * Dd + c * 32 + quad * 8);

        // 64 rows x 32 cols per wave: 4 row-groups x 2 col-tiles x 8 chunks
        f32x4 acc[4][2];
        #pragma unroll
        for (int rg = 0; rg < 4; ++rg) {
            acc[rg][0] = (f32x4){0.f, 0.f, 0.f, 0.f};
            acc[rg][1] = (f32x4){0.f, 0.f, 0.f, 0.f};
        }
        #pragma unroll
        for (int rg = 0; rg < 4; ++rg) {
            #pragma unroll
            for (int c = 0; c < 8; ++c) {
                half8 a = *(const half8*)&xT[rg * 16 + l15][c * 32 + quad * 8];
                acc[rg][0] = __builtin_amdgcn_mfma_f32_16x16x32_f16(
                    a, wf[0][c], acc[rg][0], 0, 0, 0);
                acc[rg][1] = __builtin_amdgcn_mfma_f32_16x16x32_f16(
                    a, wf[1][c], acc[rg][1], 0, 0, 0);
            }
        }

        // Epilogue
        if (which < 2) {
            f16* O = (which == 0 ? Qh : Kh) + ((size_t)b * Nn + n0) * Dd;
            #pragma unroll
            for (int rg = 0; rg < 4; ++rg) {
                #pragma unroll
                for (int ct = 0; ct < 2; ++ct) {
                    int col = col0 + ct * 16 + l15;
                    float bvv = bias[which][ct];
                    #pragma unroll
                    for (int r = 0; r < 4; ++r)
                        O[(size_t)(rg * 16 + quad * 4 + r) * Dd + col] =
                            (f16)(acc[rg][ct][r] + bvv);
                }
            }
        } else {
            f16* O = Vth + (size_t)b * Dd * Nn;
            #pragma unroll
            for (int rg = 0; rg < 4; ++rg) {
                #pragma unroll
                for (int ct = 0; ct < 2; ++ct) {
                    int col = col0 + ct * 16 + l15;
                    float bvv = bias[2][ct];
                    half4 o;
                    #pragma unroll
                    for (int r = 0; r < 4; ++r) o[r] = (f16)(acc[rg][ct][r] + bvv);
                    *(half4*)&O[(size_t)col * Nn + n0 + rg * 16 + quad * 4] = o;
                }
            }
        }
    }
}

// ---------------------------------------------------------------------------
// Kernel 2: MFMA flash attention = R4/R5 winner (T14 async-STAGE + K dbuf,
// 121 us) + two byte-local edits:
//   (a) Ps row stride 136 -> 140 f16: publish-write bank conflict 4-way ->
//       2-way/free (quads land on disjoint bank octets).
//   (b) T5 s_setprio(1) around the S and PV MFMA clusters.
// R6's T15 pipeline REVERTED: it forced ~240 live regs -> scratch spill
// (WRITE_SIZE 16.6 MB -> 820 MB, attn 3x slower).
// ---------------------------------------------------------------------------
__global__ __launch_bounds__(512, 2) void attn_mfma(
    const f16* __restrict__ Qh, const f16* __restrict__ Kh,
    const f16* __restrict__ Vth, f16* __restrict__ Opart,
    float* __restrict__ mpart, float* __restrict__ lpart)
{
    __shared__ __align__(16) f16 Ks[2][BK][264];  // 135168 B, double-buffered
    __shared__ float alpha_s[8][16];              //   512 B
    __shared__ float l_sh[8][16];                 //   512 B

    const int t    = threadIdx.x;
    const int wave = t >> 6, lane = t & 63;
    const int quad = lane >> 4, l15 = lane & 15;
    const int b    = blockIdx.y;
    const int s    = blockIdx.z;
    const int q0   = blockIdx.x * BQ;
    const int qw   = q0 + wave * 16;       // this wave's S-phase q rows
    const int kvlen = Nn / SPLIT;
    const int kv0  = s * kvlen;

    // Q A-fragments, pre-scaled by log2(e)
    half8 qf[8];
    const f16* Qrow = Qh + ((size_t)b * Nn + qw + l15) * Dd + quad * 8;
    #pragma unroll
    for (int c = 0; c < 8; ++c) {
        qf[c] = *(const half8*)(Qrow + c * 32);
        qf[c] = qf[c] * (f16)LOG2E;
    }

    // acc[qb*2+dt]: q-block qb (0..7), d-cols 32*wave + dt*16 + l15 (dt 0..1)
    f32x4 acc[16];
    #pragma unroll
    for (int n = 0; n < 16; ++n) acc[n] = (f32x4){0.f, 0.f, 0.f, 0.f};
    f32x4 m4 = {-1e30f, -1e30f, -1e30f, -1e30f};
    f32x4 l4 = {0.f, 0.f, 0.f, 0.f};

    const f16* Kb   = Kh + (size_t)b * Nn * Dd;
    const f16* Vrow = Vth + (size_t)b * Dd * Nn
                    + (size_t)(wave * 32 + l15) * Nn + quad * 8;

    // Prologue: stage first K tile into Ks[0] (exposed once per block)
    #pragma unroll
    for (int i = 0; i < 8; ++i) {
        int u = t + i * 512;
        int r = u >> 5, c = u & 31;
        *(half8*)&Ks[0][r][c * 8] =
            *(const half8*)(Kb + (size_t)(kv0 + r) * Dd + c * 8);
    }
    __syncthreads();

    int buf = 0;
    for (int k0 = kv0; k0 < kv0 + kvlen; k0 += BK) {
        // T14 issue-early: next K tile global loads -> registers. Consumed
        // (ds_write) only after PV, ~15K cycles later: latency fully hidden.
        const int kn = k0 + BK;
        const bool havenext = kn < kv0 + kvlen;   // block-uniform
        half8 kreg[8];
        if (havenext) {
            #pragma unroll
            for (int i = 0; i < 8; ++i) {
                int u = t + i * 512;
                int r = u >> 5, c = u & 31;
                kreg[i] = *(const half8*)(Kb + (size_t)(kn + r) * Dd + c * 8);
            }
        }

        // V loads for THIS tile: 2 d-tiles x 4 kv-quarters; consumed in PV
        half8 vbf[2][4];
        #pragma unroll
        for (int dt = 0; dt < 2; ++dt) {
            #pragma unroll
            for (int cbb = 0; cbb < 4; ++cbb)
                vbf[dt][cbb] = *(const half8*)(Vrow + (size_t)dt * 16 * Nn + k0 + cbb * 32);
        }

        // S = Q K^T (log2 domain) from Ks[buf], eight 16x16 col-blocks
        f32x4 S[8];
        #pragma unroll
        for (int cb = 0; cb < 8; ++cb) S[cb] = (f32x4){0.f, 0.f, 0.f, 0.f};
        __builtin_amdgcn_s_setprio(1);
        #pragma unroll
        for (int c = 0; c < 8; ++c) {
            #pragma unroll
            for (int cb = 0; cb < 8; ++cb) {
                half8 kb = *(const half8*)&Ks[buf][cb * 16 + l15][c * 32 + quad * 8];
                S[cb] = __builtin_amdgcn_mfma_f32_16x16x32_f16(qf[c], kb, S[cb], 0, 0, 0);
            }
        }
        __builtin_amdgcn_s_setprio(0);

        // Online softmax (exp2 domain), DPP reductions; P computed in-place
        f32x4 tmax = S[0];
        #pragma unroll
        for (int cb = 1; cb < 8; ++cb) {
            tmax.x = fmaxf(tmax.x, S[cb].x); tmax.y = fmaxf(tmax.y, S[cb].y);
            tmax.z = fmaxf(tmax.z, S[cb].z); tmax.w = fmaxf(tmax.w, S[cb].w);
        }
        tmax.x = red16_max(tmax.x); tmax.y = red16_max(tmax.y);
        tmax.z = red16_max(tmax.z); tmax.w = red16_max(tmax.w);
        f32x4 newm;
        newm.x = fmaxf(m4.x, tmax.x); newm.y = fmaxf(m4.y, tmax.y);
        newm.z = fmaxf(m4.z, tmax.z); newm.w = fmaxf(m4.w, tmax.w);
        f32x4 al;
        al.x = __builtin_amdgcn_exp2f(m4.x - newm.x);
        al.y = __builtin_amdgcn_exp2f(m4.y - newm.y);
        al.z = __builtin_amdgcn_exp2f(m4.z - newm.z);
        al.w = __builtin_amdgcn_exp2f(m4.w - newm.w);
        #pragma unroll
        for (int cb = 0; cb < 8; ++cb) {       // P overwrites S (reg saver)
            S[cb].x = __builtin_amdgcn_exp2f(S[cb].x - newm.x);
            S[cb].y = __builtin_amdgcn_exp2f(S[cb].y - newm.y);
            S[cb].z = __builtin_amdgcn_exp2f(S[cb].z - newm.z);
            S[cb].w = __builtin_amdgcn_exp2f(S[cb].w - newm.w);
        }
        f32x4 rsum = S[0];
        #pragma unroll
        for (int cb = 1; cb < 8; ++cb) rsum += S[cb];
        rsum.x = red16_sum(rsum.x); rsum.y = red16_sum(rsum.y);
        rsum.z = red16_sum(rsum.z); rsum.w = red16_sum(rsum.w);
        l4 = l4 * al + rsum;
        m4 = newm;

        __syncthreads();   // B2: every wave's S-phase reads of Ks[buf] done

        // Publish P (f16) and alpha into the alias of Ks[buf] (K tile dead)
        f16 (*Ps)[16][PSTRIDE] = (f16 (*)[16][PSTRIDE])&Ks[buf][0][0];
        const int pr = quad * 4;
        #pragma unroll
        for (int cb = 0; cb < 8; ++cb) {
            Ps[wave][pr + 0][cb * 16 + l15] = (f16)S[cb].x;
            Ps[wave][pr + 1][cb * 16 + l15] = (f16)S[cb].y;
            Ps[wave][pr + 2][cb * 16 + l15] = (f16)S[cb].z;
            Ps[wave][pr + 3][cb * 16 + l15] = (f16)S[cb].w;
        }
        if (l15 == 0) {
            float4 a4 = {al.x, al.y, al.z, al.w};
            *(float4*)&alpha_s[wave][pr] = a4;
        }
        __syncthreads();   // C: Ps/alpha visible

        // Rescale O by each q-block's alpha (skip when converged)
        float4 alq[8];
        int need = 0;
        #pragma unroll
        for (int qb = 0; qb < 8; ++qb) {
            alq[qb] = *(const float4*)&alpha_s[qb][pr];
            need |= (alq[qb].x != 1.f) | (alq[qb].y != 1.f) |
                    (alq[qb].z != 1.f) | (alq[qb].w != 1.f);
        }
        if (__any(need)) {
            #pragma unroll
            for (int qb = 0; qb < 8; ++qb) {
                f32x4 a = {alq[qb].x, alq[qb].y, alq[qb].z, alq[qb].w};
                acc[qb * 2 + 0] *= a;
                acc[qb * 2 + 1] *= a;
            }
        }

        // PV: 8 q-blocks x 2 d-tiles x 4 kv-quarters; A-frag one b128 each
        __builtin_amdgcn_s_setprio(1);
        #pragma unroll
        for (int qb = 0; qb < 8; ++qb) {
            #pragma unroll
            for (int cbb = 0; cbb < 4; ++cbb) {
                half8 ap = *(const half8*)&Ps[qb][l15][cbb * 32 + quad * 8];
                acc[qb * 2 + 0] = __builtin_amdgcn_mfma_f32_16x16x32_f16(
                    ap, vbf[0][cbb], acc[qb * 2 + 0], 0, 0, 0);
                acc[qb * 2 + 1] = __builtin_amdgcn_mfma_f32_16x16x32_f16(
                    ap, vbf[1][cbb], acc[qb * 2 + 1], 0, 0, 0);
            }
        }
        __builtin_amdgcn_s_setprio(0);

        // T14 write-late: commit prefetched K tile to the OTHER buffer.
        if (havenext) {
            #pragma unroll
            for (int i = 0; i < 8; ++i) {
                int u = t + i * 512;
                int r = u >> 5, c = u & 31;
                *(half8*)&Ks[buf ^ 1][r][c * 8] = kreg[i];
            }
            buf ^= 1;
        }
        __syncthreads();   // D: Ks[buf] ready for next tile's S phase
    }

    // Publish l, write m/l partials (this wave's own 16 q rows)
    if (l15 == 0) {
        const int pr = quad * 4;
        float4 lv = {l4.x, l4.y, l4.z, l4.w};
        *(float4*)&l_sh[wave][pr] = lv;
        float mv[4] = {m4.x, m4.y, m4.z, m4.w};
        float lvv[4] = {l4.x, l4.y, l4.z, l4.w};
        #pragma unroll
        for (int r = 0; r < 4; ++r) {
            int n = qw + pr + r;
            mpart[(size_t)(s * Bb + b) * Nn + n] = mv[r];
            lpart[(size_t)(s * Bb + b) * Nn + n] = lvv[r];
        }
    }
    __syncthreads();

    // Normalize + store partial O: 8 q-blocks x this wave's 2 d-tiles
    f16* Ob = Opart + (size_t)(s * Bb + b) * Dd * Nn;
    #pragma unroll
    for (int qb = 0; qb < 8; ++qb) {
        float4 lq = *(const float4*)&l_sh[qb][quad * 4];
        f32x4 inv = {1.f / lq.x, 1.f / lq.y, 1.f / lq.z, 1.f / lq.w};
        #pragma unroll
        for (int dt = 0; dt < 2; ++dt) {
            int d = wave * 32 + dt * 16 + l15;
            f32x4 o = acc[qb * 2 + dt] * inv;
            half4 oh;
            oh[0] = (f16)o.x; oh[1] = (f16)o.y; oh[2] = (f16)o.z; oh[3] = (f16)o.w;
            *(half4*)&Ob[(size_t)d * Nn + q0 + qb * 16 + quad * 4] = oh;
        }
    }
}

// ---------------------------------------------------------------------------
// Kernel 3: combine split partials (exp2 domain).
// ---------------------------------------------------------------------------
__global__ __launch_bounds__(256) void combine(
    const f16* __restrict__ Opart, const float* __restrict__ mpart,
    const float* __restrict__ lpart, float* __restrict__ out)
{
    const int t = threadIdx.x;
    const int n0 = (blockIdx.x * 256 + t) * 8;
    const int d = blockIdx.y, b = blockIdx.z;

    float m[SPLIT][8], l[SPLIT][8];
    #pragma unroll
    for (int s = 0; s < SPLIT; ++s) {
        size_t base = (size_t)(s * Bb + b) * Nn + n0;
        float4 a0 = *(const float4*)&mpart[base];
        float4 a1 = *(const float4*)&mpart[base + 4];
        float4 c0 = *(const float4*)&lpart[base];
        float4 c1 = *(const float4*)&lpart[base + 4];
        m[s][0]=a0.x; m[s][1]=a0.y; m[s][2]=a0.z; m[s][3]=a0.w;
        m[s][4]=a1.x; m[s][5]=a1.y; m[s][6]=a1.z; m[s][7]=a1.w;
        l[s][0]=c0.x; l[s][1]=c0.y; l[s][2]=c0.z; l[s][3]=c0.w;
        l[s][4]=c1.x; l[s][5]=c1.y; l[s][6]=c1.z; l[s][7]=c1.w;
    }
    float w[SPLIT][8];
    #pragma unroll
    for (int jx = 0; jx < 8; ++jx) {
        float M = m[0][jx];
        #pragma unroll
        for (int s = 1; s < SPLIT; ++s) M = fmaxf(M, m[s][jx]);
        float L = 0.f;
        #pragma unroll
        for (int s = 0; s < SPLIT; ++s) {
            float ws = l[s][jx] * __builtin_amdgcn_exp2f(m[s][jx] - M);
            w[s][jx] = ws; L += ws;
        }
        float invL = 1.f / L;
        #pragma unroll
        for (int s = 0; s < SPLIT; ++s) w[s][jx] *= invL;
    }

    float o[8];
    #pragma unroll
    for (int jx = 0; jx < 8; ++jx) o[jx] = 0.f;
    #pragma unroll
    for (int s = 0; s < SPLIT; ++s) {
        half8 h = *(const half8*)&Opart[((size_t)(s * Bb + b) * Dd + d) * Nn + n0];
        #pragma unroll
        for (int jx = 0; jx < 8; ++jx) o[jx] += w[s][jx] * (float)h[jx];
    }
    float* op = out + ((size_t)b * Dd + d) * Nn + n0;
    f32x4 o0 = {o[0], o[1], o[2], o[3]};
    f32x4 o1 = {o[4], o[5], o[6], o[7]};
    *(f32x4*)op = o0;
    *(f32x4*)(op + 4) = o1;
}

extern "C" void kernel_launch(void* const* d_in, const int* in_sizes, int n_in,
                              void* d_out, int out_size, void* d_ws, size_t ws_size,
                              hipStream_t stream) {
    const float* x  = (const float*)d_in[0];
    const float* Wq = (const float*)d_in[1];
    const float* bq = (const float*)d_in[2];
    const float* Wk = (const float*)d_in[3];
    const float* bk = (const float*)d_in[4];
    const float* Wv = (const float*)d_in[5];
    const float* bv = (const float*)d_in[6];
    float* out = (float*)d_out;

    f16* Qh    = (f16*)d_ws;
    f16* Kh    = Qh + (size_t)Bb * Nn * Dd;
    f16* Vth   = Kh + (size_t)Bb * Nn * Dd;
    f16* Wt    = Vth + (size_t)Bb * Nn * Dd;
    f16* Opart = Wt + (size_t)3 * Dd * Dd;
    float* mpart = (float*)(Opart + (size_t)SPLIT * Bb * Dd * Nn);
    float* lpart = mpart + (size_t)SPLIT * Bb * Nn;

    wtrans<<<dim3(16, 3), 256, 0, stream>>>(Wq, Wk, Wv, Wt);
    qkv_fused<<<dim3(Nn / 64, 2, Bb), 256, 0, stream>>>(
        x, Wt, bq, bk, bv, Qh, Kh, Vth);
    attn_mfma<<<dim3(Nn / BQ, Bb, SPLIT), 512, 0, stream>>>(
        Qh, Kh, Vth, Opart, mpart, lpart);
    combine<<<dim3(Nn / 2048, Dd, Bb), 256, 0, stream>>>(
        Opart, mpart, lpart, out);
}

// Round 8
// 229.572 us; speedup vs baseline: 1.8765x; 1.3271x over previous
//
#include <hip/hip_runtime.h>
#include <math.h>

#define Dd 256
#define Nn 4096
#define Bb 4
#define BQ 128      // q rows per attn block (8 waves x 16 in S phase)
#define BK 128      // kv rows per tile
#define SPLIT 2     // KV splits -> grid exactly 256 blocks = 1 round

typedef _Float16 f16;
typedef _Float16 half8 __attribute__((ext_vector_type(8)));
typedef _Float16 half4 __attribute__((ext_vector_type(4)));
typedef float f32x4 __attribute__((ext_vector_type(4)));

#define LOG2E 1.4426950408889634f

// DPP row_ror butterfly over 16-lane rows (VALU pipe, not LDS)
template <int CTRL>
__device__ __forceinline__ float dppf(float x) {
    int r = __builtin_amdgcn_update_dpp(0, __builtin_bit_cast(int, x),
                                        CTRL, 0xF, 0xF, false);
    return __builtin_bit_cast(float, r);
}
__device__ __forceinline__ float red16_max(float x) {
    x = fmaxf(x, dppf<0x128>(x));
    x = fmaxf(x, dppf<0x124>(x));
    x = fmaxf(x, dppf<0x122>(x));
    x = fmaxf(x, dppf<0x121>(x));
    return x;
}
__device__ __forceinline__ float red16_sum(float x) {
    x += dppf<0x128>(x); x += dppf<0x124>(x);
    x += dppf<0x122>(x); x += dppf<0x121>(x);
    return x;
}

// ---------------------------------------------------------------------------
// Kernel 1: QKV projection, R21 = R5 structure (W in registers, 1 barrier,
// 256-thread blocks, 2 blocks/CU) + wtrans FOLDED IN: W fragments are built
// directly from the f32 W with on-the-fly f16 cast. Lane (quad,l15) reads
// 8 scalars W[(c*32+quad*8+i)*256 + col]; consecutive l15 -> 64B-coalesced;
// W is 768 KB total -> L2/L3-resident after first touch. Removes the
// wtrans dispatch and the Wt LDS/HBM round-trip entirely.
// ---------------------------------------------------------------------------
__global__ __launch_bounds__(256) void qkv_fused(
    const float* __restrict__ x,
    const float* __restrict__ Wq, const float* __restrict__ Wk,
    const float* __restrict__ Wv,
    const float* __restrict__ bq, const float* __restrict__ bk,
    const float* __restrict__ bv,
    f16* __restrict__ Qh, f16* __restrict__ Kh, f16* __restrict__ Vth)
{
    __shared__ __align__(16) f16 xT[64][264];   // 33792 B

    const int t = threadIdx.x;
    const int wave = t >> 6, lane = t & 63, quad = lane >> 4, l15 = lane & 15;
    const int n0  = blockIdx.x * 64;
    const int ch  = blockIdx.y;           // col half: [128*ch, 128*ch+128)
    const int b   = blockIdx.z;
    const int col0 = ch * 128 + wave * 32;  // this wave's 32 out-cols

    // Stage xT[n][d] = (f16) x[b][d][n0+n]; 256 threads x 16 float4 reads
    const float* xb = x + (size_t)b * Dd * Nn;
    #pragma unroll
    for (int i = 0; i < 16; ++i) {
        int u = t + i * 256, d = u >> 4, nq = (u & 15) * 4;
        float4 v4 = *(const float4*)&xb[(size_t)d * Nn + n0 + nq];
        xT[nq + 0][d] = (f16)v4.x; xT[nq + 1][d] = (f16)v4.y;
        xT[nq + 2][d] = (f16)v4.z; xT[nq + 3][d] = (f16)v4.w;
    }

    // Biases for this wave's two col-tiles (direct, no LDS)
    float bias[3][2];
    #pragma unroll
    for (int ct = 0; ct < 2; ++ct) {
        int col = col0 + ct * 16 + l15;
        bias[0][ct] = bq[col]; bias[1][ct] = bk[col]; bias[2][ct] = bv[col];
    }

    __syncthreads();   // the ONLY barrier: xT visible, read-only hereafter

    #pragma unroll
    for (int which = 0; which < 3; ++which) {
        const float* Wf = which == 0 ? Wq : (which == 1 ? Wk : Wv);

        // B-fragments straight from f32 W (transpose-by-addressing + cast):
        // wf[ct][c][i] = (f16) W[(c*32+quad*8+i)][col0+ct*16+l15]
        half8 wf[2][8];
        #pragma unroll
        for (int ct = 0; ct < 2; ++ct) {
            int col = col0 + ct * 16 + l15;
            #pragma unroll
            for (int c = 0; c < 8; ++c) {
                half8 w;
                #pragma unroll
                for (int i = 0; i < 8; ++i)
                    w[i] = (f16)Wf[(size_t)(c * 32 + quad * 8 + i) * Dd + col];
                wf[ct][c] = w;
            }
        }

        // 64 rows x 32 cols per wave: 4 row-groups x 2 col-tiles x 8 chunks
        f32x4 acc[4][2];
        #pragma unroll
        for (int rg = 0; rg < 4; ++rg) {
            acc[rg][0] = (f32x4){0.f, 0.f, 0.f, 0.f};
            acc[rg][1] = (f32x4){0.f, 0.f, 0.f, 0.f};
        }
        #pragma unroll
        for (int rg = 0; rg < 4; ++rg) {
            #pragma unroll
            for (int c = 0; c < 8; ++c) {
                half8 a = *(const half8*)&xT[rg * 16 + l15][c * 32 + quad * 8];
                acc[rg][0] = __builtin_amdgcn_mfma_f32_16x16x32_f16(
                    a, wf[0][c], acc[rg][0], 0, 0, 0);
                acc[rg][1] = __builtin_amdgcn_mfma_f32_16x16x32_f16(
                    a, wf[1][c], acc[rg][1], 0, 0, 0);
            }
        }

        // Epilogue
        if (which < 2) {
            f16* O = (which == 0 ? Qh : Kh) + ((size_t)b * Nn + n0) * Dd;
            #pragma unroll
            for (int rg = 0; rg < 4; ++rg) {
                #pragma unroll
                for (int ct = 0; ct < 2; ++ct) {
                    int col = col0 + ct * 16 + l15;
                    float bvv = bias[which][ct];
                    #pragma unroll
                    for (int r = 0; r < 4; ++r)
                        O[(size_t)(rg * 16 + quad * 4 + r) * Dd + col] =
                            (f16)(acc[rg][ct][r] + bvv);
                }
            }
        } else {
            f16* O = Vth + (size_t)b * Dd * Nn;
            #pragma unroll
            for (int rg = 0; rg < 4; ++rg) {
                #pragma unroll
                for (int ct = 0; ct < 2; ++ct) {
                    int col = col0 + ct * 16 + l15;
                    float bvv = bias[2][ct];
                    half4 o;
                    #pragma unroll
                    for (int r = 0; r < 4; ++r) o[r] = (f16)(acc[rg][ct][r] + bvv);
                    *(half4*)&O[(size_t)col * Nn + n0 + rg * 16 + quad * 4] = o;
                }
            }
        }
    }
}

// ---------------------------------------------------------------------------
// Kernel 2: MFMA flash attention = exact R4/R5 winner (120.7 us, measured
// twice). T14 async-STAGE + double-buffered K; Ps (stride 136, 16B-aligned
// rows) aliases the dead Ks buffer. R7's PSTRIDE=140 (misaligned b128
// reads) and setprio (lockstep regime -> null/harm) are REVERTED.
// ---------------------------------------------------------------------------
__global__ __launch_bounds__(512, 2) void attn_mfma(
    const f16* __restrict__ Qh, const f16* __restrict__ Kh,
    const f16* __restrict__ Vth, f16* __restrict__ Opart,
    float* __restrict__ mpart, float* __restrict__ lpart)
{
    __shared__ __align__(16) f16 Ks[2][BK][264];  // 135168 B, double-buffered
    __shared__ float alpha_s[8][16];              //   512 B
    __shared__ float l_sh[8][16];                 //   512 B

    const int t    = threadIdx.x;
    const int wave = t >> 6, lane = t & 63;
    const int quad = lane >> 4, l15 = lane & 15;
    const int b    = blockIdx.y;
    const int s    = blockIdx.z;
    const int q0   = blockIdx.x * BQ;
    const int qw   = q0 + wave * 16;       // this wave's S-phase q rows
    const int kvlen = Nn / SPLIT;
    const int kv0  = s * kvlen;

    // Q A-fragments, pre-scaled by log2(e)
    half8 qf[8];
    const f16* Qrow = Qh + ((size_t)b * Nn + qw + l15) * Dd + quad * 8;
    #pragma unroll
    for (int c = 0; c < 8; ++c) {
        qf[c] = *(const half8*)(Qrow + c * 32);
        qf[c] = qf[c] * (f16)LOG2E;
    }

    // acc[qb*2+dt]: q-block qb (0..7), d-cols 32*wave + dt*16 + l15 (dt 0..1)
    f32x4 acc[16];
    #pragma unroll
    for (int n = 0; n < 16; ++n) acc[n] = (f32x4){0.f, 0.f, 0.f, 0.f};
    f32x4 m4 = {-1e30f, -1e30f, -1e30f, -1e30f};
    f32x4 l4 = {0.f, 0.f, 0.f, 0.f};

    const f16* Kb   = Kh + (size_t)b * Nn * Dd;
    const f16* Vrow = Vth + (size_t)b * Dd * Nn
                    + (size_t)(wave * 32 + l15) * Nn + quad * 8;

    // Prologue: stage first K tile into Ks[0] (exposed once per block)
    #pragma unroll
    for (int i = 0; i < 8; ++i) {
        int u = t + i * 512;
        int r = u >> 5, c = u & 31;
        *(half8*)&Ks[0][r][c * 8] =
            *(const half8*)(Kb + (size_t)(kv0 + r) * Dd + c * 8);
    }
    __syncthreads();

    int buf = 0;
    for (int k0 = kv0; k0 < kv0 + kvlen; k0 += BK) {
        // T14 issue-early: next K tile global loads -> registers. Consumed
        // (ds_write) only after PV, ~15K cycles later: latency fully hidden.
        const int kn = k0 + BK;
        const bool havenext = kn < kv0 + kvlen;   // block-uniform
        half8 kreg[8];
        if (havenext) {
            #pragma unroll
            for (int i = 0; i < 8; ++i) {
                int u = t + i * 512;
                int r = u >> 5, c = u & 31;
                kreg[i] = *(const half8*)(Kb + (size_t)(kn + r) * Dd + c * 8);
            }
        }

        // V loads for THIS tile: 2 d-tiles x 4 kv-quarters; consumed in PV
        half8 vbf[2][4];
        #pragma unroll
        for (int dt = 0; dt < 2; ++dt) {
            #pragma unroll
            for (int cbb = 0; cbb < 4; ++cbb)
                vbf[dt][cbb] = *(const half8*)(Vrow + (size_t)dt * 16 * Nn + k0 + cbb * 32);
        }

        // S = Q K^T (log2 domain) from Ks[buf], eight 16x16 col-blocks
        f32x4 S[8];
        #pragma unroll
        for (int cb = 0; cb < 8; ++cb) S[cb] = (f32x4){0.f, 0.f, 0.f, 0.f};
        #pragma unroll
        for (int c = 0; c < 8; ++c) {
            #pragma unroll
            for (int cb = 0; cb < 8; ++cb) {
                half8 kb = *(const half8*)&Ks[buf][cb * 16 + l15][c * 32 + quad * 8];
                S[cb] = __builtin_amdgcn_mfma_f32_16x16x32_f16(qf[c], kb, S[cb], 0, 0, 0);
            }
        }

        // Online softmax (exp2 domain), DPP reductions; P computed in-place
        f32x4 tmax = S[0];
        #pragma unroll
        for (int cb = 1; cb < 8; ++cb) {
            tmax.x = fmaxf(tmax.x, S[cb].x); tmax.y = fmaxf(tmax.y, S[cb].y);
            tmax.z = fmaxf(tmax.z, S[cb].z); tmax.w = fmaxf(tmax.w, S[cb].w);
        }
        tmax.x = red16_max(tmax.x); tmax.y = red16_max(tmax.y);
        tmax.z = red16_max(tmax.z); tmax.w = red16_max(tmax.w);
        f32x4 newm;
        newm.x = fmaxf(m4.x, tmax.x); newm.y = fmaxf(m4.y, tmax.y);
        newm.z = fmaxf(m4.z, tmax.z); newm.w = fmaxf(m4.w, tmax.w);
        f32x4 al;
        al.x = __builtin_amdgcn_exp2f(m4.x - newm.x);
        al.y = __builtin_amdgcn_exp2f(m4.y - newm.y);
        al.z = __builtin_amdgcn_exp2f(m4.z - newm.z);
        al.w = __builtin_amdgcn_exp2f(m4.w - newm.w);
        #pragma unroll
        for (int cb = 0; cb < 8; ++cb) {       // P overwrites S (reg saver)
            S[cb].x = __builtin_amdgcn_exp2f(S[cb].x - newm.x);
            S[cb].y = __builtin_amdgcn_exp2f(S[cb].y - newm.y);
            S[cb].z = __builtin_amdgcn_exp2f(S[cb].z - newm.z);
            S[cb].w = __builtin_amdgcn_exp2f(S[cb].w - newm.w);
        }
        f32x4 rsum = S[0];
        #pragma unroll
        for (int cb = 1; cb < 8; ++cb) rsum += S[cb];
        rsum.x = red16_sum(rsum.x); rsum.y = red16_sum(rsum.y);
        rsum.z = red16_sum(rsum.z); rsum.w = red16_sum(rsum.w);
        l4 = l4 * al + rsum;
        m4 = newm;

        __syncthreads();   // B2: every wave's S-phase reads of Ks[buf] done

        // Publish P (f16) and alpha into the alias of Ks[buf] (K tile dead)
        f16 (*Ps)[16][136] = (f16 (*)[16][136])&Ks[buf][0][0];
        const int pr = quad * 4;
        #pragma unroll
        for (int cb = 0; cb < 8; ++cb) {
            Ps[wave][pr + 0][cb * 16 + l15] = (f16)S[cb].x;
            Ps[wave][pr + 1][cb * 16 + l15] = (f16)S[cb].y;
            Ps[wave][pr + 2][cb * 16 + l15] = (f16)S[cb].z;
            Ps[wave][pr + 3][cb * 16 + l15] = (f16)S[cb].w;
        }
        if (l15 == 0) {
            float4 a4 = {al.x, al.y, al.z, al.w};
            *(float4*)&alpha_s[wave][pr] = a4;
        }
        __syncthreads();   // C: Ps/alpha visible

        // Rescale O by each q-block's alpha (skip when converged)
        float4 alq[8];
        int need = 0;
        #pragma unroll
        for (int qb = 0; qb < 8; ++qb) {
            alq[qb] = *(const float4*)&alpha_s[qb][pr];
            need |= (alq[qb].x != 1.f) | (alq[qb].y != 1.f) |
                    (alq[qb].z != 1.f) | (alq[qb].w != 1.f);
        }
        if (__any(need)) {
            #pragma unroll
            for (int qb = 0; qb < 8; ++qb) {
                f32x4 a = {alq[qb].x, alq[qb].y, alq[qb].z, alq[qb].w};
                acc[qb * 2 + 0] *= a;
                acc[qb * 2 + 1] *= a;
            }
        }

        // PV: 8 q-blocks x 2 d-tiles x 4 kv-quarters; A-frag one b128 each
        #pragma unroll
        for (int qb = 0; qb < 8; ++qb) {
            #pragma unroll
            for (int cbb = 0; cbb < 4; ++cbb) {
                half8 ap = *(const half8*)&Ps[qb][l15][cbb * 32 + quad * 8];
                acc[qb * 2 + 0] = __builtin_amdgcn_mfma_f32_16x16x32_f16(
                    ap, vbf[0][cbb], acc[qb * 2 + 0], 0, 0, 0);
                acc[qb * 2 + 1] = __builtin_amdgcn_mfma_f32_16x16x32_f16(
                    ap, vbf[1][cbb], acc[qb * 2 + 1], 0, 0, 0);
            }
        }

        // T14 write-late: commit prefetched K tile to the OTHER buffer.
        if (havenext) {
            #pragma unroll
            for (int i = 0; i < 8; ++i) {
                int u = t + i * 512;
                int r = u >> 5, c = u & 31;
                *(half8*)&Ks[buf ^ 1][r][c * 8] = kreg[i];
            }
            buf ^= 1;
        }
        __syncthreads();   // D: Ks[buf] ready for next tile's S phase
    }

    // Publish l, write m/l partials (this wave's own 16 q rows)
    if (l15 == 0) {
        const int pr = quad * 4;
        float4 lv = {l4.x, l4.y, l4.z, l4.w};
        *(float4*)&l_sh[wave][pr] = lv;
        float mv[4] = {m4.x, m4.y, m4.z, m4.w};
        float lvv[4] = {l4.x, l4.y, l4.z, l4.w};
        #pragma unroll
        for (int r = 0; r < 4; ++r) {
            int n = qw + pr + r;
            mpart[(size_t)(s * Bb + b) * Nn + n] = mv[r];
            lpart[(size_t)(s * Bb + b) * Nn + n] = lvv[r];
        }
    }
    __syncthreads();

    // Normalize + store partial O: 8 q-blocks x this wave's 2 d-tiles
    f16* Ob = Opart + (size_t)(s * Bb + b) * Dd * Nn;
    #pragma unroll
    for (int qb = 0; qb < 8; ++qb) {
        float4 lq = *(const float4*)&l_sh[qb][quad * 4];
        f32x4 inv = {1.f / lq.x, 1.f / lq.y, 1.f / lq.z, 1.f / lq.w};
        #pragma unroll
        for (int dt = 0; dt < 2; ++dt) {
            int d = wave * 32 + dt * 16 + l15;
            f32x4 o = acc[qb * 2 + dt] * inv;
            half4 oh;
            oh[0] = (f16)o.x; oh[1] = (f16)o.y; oh[2] = (f16)o.z; oh[3] = (f16)o.w;
            *(half4*)&Ob[(size_t)d * Nn + q0 + qb * 16 + quad * 4] = oh;
        }
    }
}

// ---------------------------------------------------------------------------
// Kernel 3: combine split partials (exp2 domain).
// ---------------------------------------------------------------------------
__global__ __launch_bounds__(256) void combine(
    const f16* __restrict__ Opart, const float* __restrict__ mpart,
    const float* __restrict__ lpart, float* __restrict__ out)
{
    const int t = threadIdx.x;
    const int n0 = (blockIdx.x * 256 + t) * 8;
    const int d = blockIdx.y, b = blockIdx.z;

    float m[SPLIT][8], l[SPLIT][8];
    #pragma unroll
    for (int s = 0; s < SPLIT; ++s) {
        size_t base = (size_t)(s * Bb + b) * Nn + n0;
        float4 a0 = *(const float4*)&mpart[base];
        float4 a1 = *(const float4*)&mpart[base + 4];
        float4 c0 = *(const float4*)&lpart[base];
        float4 c1 = *(const float4*)&lpart[base + 4];
        m[s][0]=a0.x; m[s][1]=a0.y; m[s][2]=a0.z; m[s][3]=a0.w;
        m[s][4]=a1.x; m[s][5]=a1.y; m[s][6]=a1.z; m[s][7]=a1.w;
        l[s][0]=c0.x; l[s][1]=c0.y; l[s][2]=c0.z; l[s][3]=c0.w;
        l[s][4]=c1.x; l[s][5]=c1.y; l[s][6]=c1.z; l[s][7]=c1.w;
    }
    float w[SPLIT][8];
    #pragma unroll
    for (int jx = 0; jx < 8; ++jx) {
        float M = m[0][jx];
        #pragma unroll
        for (int s = 1; s < SPLIT; ++s) M = fmaxf(M, m[s][jx]);
        float L = 0.f;
        #pragma unroll
        for (int s = 0; s < SPLIT; ++s) {
            float ws = l[s][jx] * __builtin_amdgcn_exp2f(m[s][jx] - M);
            w[s][jx] = ws; L += ws;
        }
        float invL = 1.f / L;
        #pragma unroll
        for (int s = 0; s < SPLIT; ++s) w[s][jx] *= invL;
    }

    float o[8];
    #pragma unroll
    for (int jx = 0; jx < 8; ++jx) o[jx] = 0.f;
    #pragma unroll
    for (int s = 0; s < SPLIT; ++s) {
        half8 h = *(const half8*)&Opart[((size_t)(s * Bb + b) * Dd + d) * Nn + n0];
        #pragma unroll
        for (int jx = 0; jx < 8; ++jx) o[jx] += w[s][jx] * (float)h[jx];
    }
    float* op = out + ((size_t)b * Dd + d) * Nn + n0;
    f32x4 o0 = {o[0], o[1], o[2], o[3]};
    f32x4 o1 = {o[4], o[5], o[6], o[7]};
    *(f32x4*)op = o0;
    *(f32x4*)(op + 4) = o1;
}

extern "C" void kernel_launch(void* const* d_in, const int* in_sizes, int n_in,
                              void* d_out, int out_size, void* d_ws, size_t ws_size,
                              hipStream_t stream) {
    const float* x  = (const float*)d_in[0];
    const float* Wq = (const float*)d_in[1];
    const float* bq = (const float*)d_in[2];
    const float* Wk = (const float*)d_in[3];
    const float* bk = (const float*)d_in[4];
    const float* Wv = (const float*)d_in[5];
    const float* bv = (const float*)d_in[6];
    float* out = (float*)d_out;

    f16* Qh    = (f16*)d_ws;
    f16* Kh    = Qh + (size_t)Bb * Nn * Dd;
    f16* Vth   = Kh + (size_t)Bb * Nn * Dd;
    f16* Opart = Vth + (size_t)Bb * Nn * Dd;
    float* mpart = (float*)(Opart + (size_t)SPLIT * Bb * Dd * Nn);
    float* lpart = mpart + (size_t)SPLIT * Bb * Nn;

    qkv_fused<<<dim3(Nn / 64, 2, Bb), 256, 0, stream>>>(
        x, Wq, Wk, Wv, bq, bk, bv, Qh, Kh, Vth);
    attn_mfma<<<dim3(Nn / BQ, Bb, SPLIT), 512, 0, stream>>>(
        Qh, Kh, Vth, Opart, mpart, lpart);
    combine<<<dim3(Nn / 2048, Dd, Bb), 256, 0, stream>>>(
        Opart, mpart, lpart, out);
}

// Round 9
// 209.155 us; speedup vs baseline: 2.0596x; 1.0976x over previous
//
#include <hip/hip_runtime.h>
#include <math.h>

#define Dd 256
#define Nn 4096
#define Bb 4
#define BQ 128      // q rows per attn block (8 waves x 16 in S phase)
#define BK 128      // kv rows per tile
#define SPLIT 2     // KV splits -> grid exactly 256 blocks = 1 round

typedef _Float16 f16;
typedef _Float16 half8 __attribute__((ext_vector_type(8)));
typedef _Float16 half4 __attribute__((ext_vector_type(4)));
typedef float f32x4 __attribute__((ext_vector_type(4)));

#define LOG2E 1.4426950408889634f

// DPP row_ror butterfly over 16-lane rows (VALU pipe, not LDS)
template <int CTRL>
__device__ __forceinline__ float dppf(float x) {
    int r = __builtin_amdgcn_update_dpp(0, __builtin_bit_cast(int, x),
                                        CTRL, 0xF, 0xF, false);
    return __builtin_bit_cast(float, r);
}
__device__ __forceinline__ float red16_max(float x) {
    x = fmaxf(x, dppf<0x128>(x));
    x = fmaxf(x, dppf<0x124>(x));
    x = fmaxf(x, dppf<0x122>(x));
    x = fmaxf(x, dppf<0x121>(x));
    return x;
}
__device__ __forceinline__ float red16_sum(float x) {
    x += dppf<0x128>(x); x += dppf<0x124>(x);
    x += dppf<0x122>(x); x += dppf<0x121>(x);
    return x;
}

// ---------------------------------------------------------------------------
// Kernel 0: W transpose+cast.  Wt[which][d'][d] = (f16) W[d][d']
// (Restored: R8's fold into qkv replaced 48 b128 loads/wave with 384 scalar
// f32 loads/thread -> +20 us. Vectorized staging wins.)
// ---------------------------------------------------------------------------
__global__ __launch_bounds__(256) void wtrans(
    const float* __restrict__ Wq, const float* __restrict__ Wk,
    const float* __restrict__ Wv, f16* __restrict__ Wt)
{
    __shared__ float ld[64][65];
    const int which = blockIdx.y;
    const float* W = which == 0 ? Wq : (which == 1 ? Wk : Wv);
    const int tr = (blockIdx.x >> 2) * 64;
    const int tc = (blockIdx.x & 3) * 64;
    const int t = threadIdx.x;
    #pragma unroll
    for (int i = 0; i < 16; ++i) {
        int u = t + i * 256, r = u >> 6, c = u & 63;
        ld[r][c] = W[(size_t)(tr + r) * Dd + tc + c];
    }
    __syncthreads();
    f16* Wo = Wt + (size_t)which * Dd * Dd;
    #pragma unroll
    for (int i = 0; i < 16; ++i) {
        int u = t + i * 256, cp = u >> 6, rp = u & 63;
        Wo[(size_t)(tc + cp) * Dd + tr + rp] = (f16)ld[rp][cp];
    }
}

// ---------------------------------------------------------------------------
// Kernel 1: QKV projection (exact R5 winner): W fragments in registers from
// f16 Wt (b128 loads), xT staged once, 1 barrier, 256-thr blocks, 2/CU.
// ---------------------------------------------------------------------------
__global__ __launch_bounds__(256) void qkv_fused(
    const float* __restrict__ x, const f16* __restrict__ Wt,
    const float* __restrict__ bq, const float* __restrict__ bk,
    const float* __restrict__ bv,
    f16* __restrict__ Qh, f16* __restrict__ Kh, f16* __restrict__ Vth)
{
    __shared__ __align__(16) f16 xT[64][264];   // 33792 B

    const int t = threadIdx.x;
    const int wave = t >> 6, lane = t & 63, quad = lane >> 4, l15 = lane & 15;
    const int n0  = blockIdx.x * 64;
    const int ch  = blockIdx.y;           // col half: [128*ch, 128*ch+128)
    const int b   = blockIdx.z;
    const int col0 = ch * 128 + wave * 32;  // this wave's 32 out-cols

    // Stage xT[n][d] = (f16) x[b][d][n0+n]; 256 threads x 16 float4 reads
    const float* xb = x + (size_t)b * Dd * Nn;
    #pragma unroll
    for (int i = 0; i < 16; ++i) {
        int u = t + i * 256, d = u >> 4, nq = (u & 15) * 4;
        float4 v4 = *(const float4*)&xb[(size_t)d * Nn + n0 + nq];
        xT[nq + 0][d] = (f16)v4.x; xT[nq + 1][d] = (f16)v4.y;
        xT[nq + 2][d] = (f16)v4.z; xT[nq + 3][d] = (f16)v4.w;
    }

    // Biases for this wave's two col-tiles (direct, no LDS)
    float bias[3][2];
    #pragma unroll
    for (int ct = 0; ct < 2; ++ct) {
        int col = col0 + ct * 16 + l15;
        bias[0][ct] = bq[col]; bias[1][ct] = bk[col]; bias[2][ct] = bv[col];
    }

    __syncthreads();   // the ONLY barrier: xT visible, read-only hereafter

    #pragma unroll
    for (int which = 0; which < 3; ++which) {
        // B-fragments from L2: 16 x b128 per wave, register-resident
        const f16* Wb = Wt + (size_t)which * Dd * Dd;
        half8 wf[2][8];
        #pragma unroll
        for (int ct = 0; ct < 2; ++ct)
            #pragma unroll
            for (int c = 0; c < 8; ++c)
                wf[ct][c] = *(const half8*)(Wb
                    + (size_t)(col0 + ct * 16 + l15) * Dd + c * 32 + quad * 8);

        // 64 rows x 32 cols per wave: 4 row-groups x 2 col-tiles x 8 chunks
        f32x4 acc[4][2];
        #pragma unroll
        for (int rg = 0; rg < 4; ++rg) {
            acc[rg][0] = (f32x4){0.f, 0.f, 0.f, 0.f};
            acc[rg][1] = (f32x4){0.f, 0.f, 0.f, 0.f};
        }
        #pragma unroll
        for (int rg = 0; rg < 4; ++rg) {
            #pragma unroll
            for (int c = 0; c < 8; ++c) {
                half8 a = *(const half8*)&xT[rg * 16 + l15][c * 32 + quad * 8];
                acc[rg][0] = __builtin_amdgcn_mfma_f32_16x16x32_f16(
                    a, wf[0][c], acc[rg][0], 0, 0, 0);
                acc[rg][1] = __builtin_amdgcn_mfma_f32_16x16x32_f16(
                    a, wf[1][c], acc[rg][1], 0, 0, 0);
            }
        }

        // Epilogue
        if (which < 2) {
            f16* O = (which == 0 ? Qh : Kh) + ((size_t)b * Nn + n0) * Dd;
            #pragma unroll
            for (int rg = 0; rg < 4; ++rg) {
                #pragma unroll
                for (int ct = 0; ct < 2; ++ct) {
                    int col = col0 + ct * 16 + l15;
                    float bvv = bias[which][ct];
                    #pragma unroll
                    for (int r = 0; r < 4; ++r)
                        O[(size_t)(rg * 16 + quad * 4 + r) * Dd + col] =
                            (f16)(acc[rg][ct][r] + bvv);
                }
            }
        } else {
            f16* O = Vth + (size_t)b * Dd * Nn;
            #pragma unroll
            for (int rg = 0; rg < 4; ++rg) {
                #pragma unroll
                for (int ct = 0; ct < 2; ++ct) {
                    int col = col0 + ct * 16 + l15;
                    float bvv = bias[2][ct];
                    half4 o;
                    #pragma unroll
                    for (int r = 0; r < 4; ++r) o[r] = (f16)(acc[rg][ct][r] + bvv);
                    *(half4*)&O[(size_t)col * Nn + n0 + rg * 16 + quad * 4] = o;
                }
            }
        }
    }
}

// ---------------------------------------------------------------------------
// Kernel 2: MFMA flash attention = R4/R5 winner schedule (T14 async-STAGE +
// K dbuf, 120.7 us) + ONE change: XCD-aware block mapping. Flat 256-block
// grid; pair = bid & 7 selects (b,s) so all 32 q-blocks sharing one
// (batch, kv-half) land on the SAME XCD (round-robin bid%8 -> XCD). One
// pair's working set (K 1MB + V 1MB + Q 2MB = 4MB) fits that XCD's L2 ->
// K/V prefetch loads become L2 hits -> shorter vmcnt drains at the 3
// barriers/tile (kernel is latency-bound: MfmaUtil 23% = exactly the
// 28 us MFMA floor spread over 121 us). Bijection: 256 blocks, 256%8==0.
// ---------------------------------------------------------------------------
__global__ __launch_bounds__(512, 2) void attn_mfma(
    const f16* __restrict__ Qh, const f16* __restrict__ Kh,
    const f16* __restrict__ Vth, f16* __restrict__ Opart,
    float* __restrict__ mpart, float* __restrict__ lpart)
{
    __shared__ __align__(16) f16 Ks[2][BK][264];  // 135168 B, double-buffered
    __shared__ float alpha_s[8][16];              //   512 B
    __shared__ float l_sh[8][16];                 //   512 B

    const int t    = threadIdx.x;
    const int wave = t >> 6, lane = t & 63;
    const int quad = lane >> 4, l15 = lane & 15;
    const int bid  = blockIdx.x;
    const int pair = bid & 7;              // -> XCD bid%8
    const int b    = pair & 3;
    const int s    = pair >> 2;
    const int q0   = (bid >> 3) * BQ;
    const int qw   = q0 + wave * 16;       // this wave's S-phase q rows
    const int kvlen = Nn / SPLIT;
    const int kv0  = s * kvlen;

    // Q A-fragments, pre-scaled by log2(e)
    half8 qf[8];
    const f16* Qrow = Qh + ((size_t)b * Nn + qw + l15) * Dd + quad * 8;
    #pragma unroll
    for (int c = 0; c < 8; ++c) {
        qf[c] = *(const half8*)(Qrow + c * 32);
        qf[c] = qf[c] * (f16)LOG2E;
    }

    // acc[qb*2+dt]: q-block qb (0..7), d-cols 32*wave + dt*16 + l15 (dt 0..1)
    f32x4 acc[16];
    #pragma unroll
    for (int n = 0; n < 16; ++n) acc[n] = (f32x4){0.f, 0.f, 0.f, 0.f};
    f32x4 m4 = {-1e30f, -1e30f, -1e30f, -1e30f};
    f32x4 l4 = {0.f, 0.f, 0.f, 0.f};

    const f16* Kb   = Kh + (size_t)b * Nn * Dd;
    const f16* Vrow = Vth + (size_t)b * Dd * Nn
                    + (size_t)(wave * 32 + l15) * Nn + quad * 8;

    // Prologue: stage first K tile into Ks[0] (exposed once per block)
    #pragma unroll
    for (int i = 0; i < 8; ++i) {
        int u = t + i * 512;
        int r = u >> 5, c = u & 31;
        *(half8*)&Ks[0][r][c * 8] =
            *(const half8*)(Kb + (size_t)(kv0 + r) * Dd + c * 8);
    }
    __syncthreads();

    int buf = 0;
    for (int k0 = kv0; k0 < kv0 + kvlen; k0 += BK) {
        // T14 issue-early: next K tile global loads -> registers. Consumed
        // (ds_write) only after PV, ~15K cycles later: latency fully hidden.
        const int kn = k0 + BK;
        const bool havenext = kn < kv0 + kvlen;   // block-uniform
        half8 kreg[8];
        if (havenext) {
            #pragma unroll
            for (int i = 0; i < 8; ++i) {
                int u = t + i * 512;
                int r = u >> 5, c = u & 31;
                kreg[i] = *(const half8*)(Kb + (size_t)(kn + r) * Dd + c * 8);
            }
        }

        // V loads for THIS tile: 2 d-tiles x 4 kv-quarters; consumed in PV
        half8 vbf[2][4];
        #pragma unroll
        for (int dt = 0; dt < 2; ++dt) {
            #pragma unroll
            for (int cbb = 0; cbb < 4; ++cbb)
                vbf[dt][cbb] = *(const half8*)(Vrow + (size_t)dt * 16 * Nn + k0 + cbb * 32);
        }

        // S = Q K^T (log2 domain) from Ks[buf], eight 16x16 col-blocks
        f32x4 S[8];
        #pragma unroll
        for (int cb = 0; cb < 8; ++cb) S[cb] = (f32x4){0.f, 0.f, 0.f, 0.f};
        #pragma unroll
        for (int c = 0; c < 8; ++c) {
            #pragma unroll
            for (int cb = 0; cb < 8; ++cb) {
                half8 kb = *(const half8*)&Ks[buf][cb * 16 + l15][c * 32 + quad * 8];
                S[cb] = __builtin_amdgcn_mfma_f32_16x16x32_f16(qf[c], kb, S[cb], 0, 0, 0);
            }
        }

        // Online softmax (exp2 domain), DPP reductions; P computed in-place
        f32x4 tmax = S[0];
        #pragma unroll
        for (int cb = 1; cb < 8; ++cb) {
            tmax.x = fmaxf(tmax.x, S[cb].x); tmax.y = fmaxf(tmax.y, S[cb].y);
            tmax.z = fmaxf(tmax.z, S[cb].z); tmax.w = fmaxf(tmax.w, S[cb].w);
        }
        tmax.x = red16_max(tmax.x); tmax.y = red16_max(tmax.y);
        tmax.z = red16_max(tmax.z); tmax.w = red16_max(tmax.w);
        f32x4 newm;
        newm.x = fmaxf(m4.x, tmax.x); newm.y = fmaxf(m4.y, tmax.y);
        newm.z = fmaxf(m4.z, tmax.z); newm.w = fmaxf(m4.w, tmax.w);
        f32x4 al;
        al.x = __builtin_amdgcn_exp2f(m4.x - newm.x);
        al.y = __builtin_amdgcn_exp2f(m4.y - newm.y);
        al.z = __builtin_amdgcn_exp2f(m4.z - newm.z);
        al.w = __builtin_amdgcn_exp2f(m4.w - newm.w);
        #pragma unroll
        for (int cb = 0; cb < 8; ++cb) {       // P overwrites S (reg saver)
            S[cb].x = __builtin_amdgcn_exp2f(S[cb].x - newm.x);
            S[cb].y = __builtin_amdgcn_exp2f(S[cb].y - newm.y);
            S[cb].z = __builtin_amdgcn_exp2f(S[cb].z - newm.z);
            S[cb].w = __builtin_amdgcn_exp2f(S[cb].w - newm.w);
        }
        f32x4 rsum = S[0];
        #pragma unroll
        for (int cb = 1; cb < 8; ++cb) rsum += S[cb];
        rsum.x = red16_sum(rsum.x); rsum.y = red16_sum(rsum.y);
        rsum.z = red16_sum(rsum.z); rsum.w = red16_sum(rsum.w);
        l4 = l4 * al + rsum;
        m4 = newm;

        __syncthreads();   // B2: every wave's S-phase reads of Ks[buf] done

        // Publish P (f16) and alpha into the alias of Ks[buf] (K tile dead)
        f16 (*Ps)[16][136] = (f16 (*)[16][136])&Ks[buf][0][0];
        const int pr = quad * 4;
        #pragma unroll
        for (int cb = 0; cb < 8; ++cb) {
            Ps[wave][pr + 0][cb * 16 + l15] = (f16)S[cb].x;
            Ps[wave][pr + 1][cb * 16 + l15] = (f16)S[cb].y;
            Ps[wave][pr + 2][cb * 16 + l15] = (f16)S[cb].z;
            Ps[wave][pr + 3][cb * 16 + l15] = (f16)S[cb].w;
        }
        if (l15 == 0) {
            float4 a4 = {al.x, al.y, al.z, al.w};
            *(float4*)&alpha_s[wave][pr] = a4;
        }
        __syncthreads();   // C: Ps/alpha visible

        // Rescale O by each q-block's alpha (skip when converged)
        float4 alq[8];
        int need = 0;
        #pragma unroll
        for (int qb = 0; qb < 8; ++qb) {
            alq[qb] = *(const float4*)&alpha_s[qb][pr];
            need |= (alq[qb].x != 1.f) | (alq[qb].y != 1.f) |
                    (alq[qb].z != 1.f) | (alq[qb].w != 1.f);
        }
        if (__any(need)) {
            #pragma unroll
            for (int qb = 0; qb < 8; ++qb) {
                f32x4 a = {alq[qb].x, alq[qb].y, alq[qb].z, alq[qb].w};
                acc[qb * 2 + 0] *= a;
                acc[qb * 2 + 1] *= a;
            }
        }

        // PV: 8 q-blocks x 2 d-tiles x 4 kv-quarters; A-frag one b128 each
        #pragma unroll
        for (int qb = 0; qb < 8; ++qb) {
            #pragma unroll
            for (int cbb = 0; cbb < 4; ++cbb) {
                half8 ap = *(const half8*)&Ps[qb][l15][cbb * 32 + quad * 8];
                acc[qb * 2 + 0] = __builtin_amdgcn_mfma_f32_16x16x32_f16(
                    ap, vbf[0][cbb], acc[qb * 2 + 0], 0, 0, 0);
                acc[qb * 2 + 1] = __builtin_amdgcn_mfma_f32_16x16x32_f16(
                    ap, vbf[1][cbb], acc[qb * 2 + 1], 0, 0, 0);
            }
        }

        // T14 write-late: commit prefetched K tile to the OTHER buffer.
        if (havenext) {
            #pragma unroll
            for (int i = 0; i < 8; ++i) {
                int u = t + i * 512;
                int r = u >> 5, c = u & 31;
                *(half8*)&Ks[buf ^ 1][r][c * 8] = kreg[i];
            }
            buf ^= 1;
        }
        __syncthreads();   // D: Ks[buf] ready for next tile's S phase
    }

    // Publish l, write m/l partials (this wave's own 16 q rows)
    if (l15 == 0) {
        const int pr = quad * 4;
        float4 lv = {l4.x, l4.y, l4.z, l4.w};
        *(float4*)&l_sh[wave][pr] = lv;
        float mv[4] = {m4.x, m4.y, m4.z, m4.w};
        float lvv[4] = {l4.x, l4.y, l4.z, l4.w};
        #pragma unroll
        for (int r = 0; r < 4; ++r) {
            int n = qw + pr + r;
            mpart[(size_t)(s * Bb + b) * Nn + n] = mv[r];
            lpart[(size_t)(s * Bb + b) * Nn + n] = lvv[r];
        }
    }
    __syncthreads();

    // Normalize + store partial O: 8 q-blocks x this wave's 2 d-tiles
    f16* Ob = Opart + (size_t)(s * Bb + b) * Dd * Nn;
    #pragma unroll
    for (int qb = 0; qb < 8; ++qb) {
        float4 lq = *(const float4*)&l_sh[qb][quad * 4];
        f32x4 inv = {1.f / lq.x, 1.f / lq.y, 1.f / lq.z, 1.f / lq.w};
        #pragma unroll
        for (int dt = 0; dt < 2; ++dt) {
            int d = wave * 32 + dt * 16 + l15;
            f32x4 o = acc[qb * 2 + dt] * inv;
            half4 oh;
            oh[0] = (f16)o.x; oh[1] = (f16)o.y; oh[2] = (f16)o.z; oh[3] = (f16)o.w;
            *(half4*)&Ob[(size_t)d * Nn + q0 + qb * 16 + quad * 4] = oh;
        }
    }
}

// ---------------------------------------------------------------------------
// Kernel 3: combine split partials (exp2 domain).
// ---------------------------------------------------------------------------
__global__ __launch_bounds__(256) void combine(
    const f16* __restrict__ Opart, const float* __restrict__ mpart,
    const float* __restrict__ lpart, float* __restrict__ out)
{
    const int t = threadIdx.x;
    const int n0 = (blockIdx.x * 256 + t) * 8;
    const int d = blockIdx.y, b = blockIdx.z;

    float m[SPLIT][8], l[SPLIT][8];
    #pragma unroll
    for (int s = 0; s < SPLIT; ++s) {
        size_t base = (size_t)(s * Bb + b) * Nn + n0;
        float4 a0 = *(const float4*)&mpart[base];
        float4 a1 = *(const float4*)&mpart[base + 4];
        float4 c0 = *(const float4*)&lpart[base];
        float4 c1 = *(const float4*)&lpart[base + 4];
        m[s][0]=a0.x; m[s][1]=a0.y; m[s][2]=a0.z; m[s][3]=a0.w;
        m[s][4]=a1.x; m[s][5]=a1.y; m[s][6]=a1.z; m[s][7]=a1.w;
        l[s][0]=c0.x; l[s][1]=c0.y; l[s][2]=c0.z; l[s][3]=c0.w;
        l[s][4]=c1.x; l[s][5]=c1.y; l[s][6]=c1.z; l[s][7]=c1.w;
    }
    float w[SPLIT][8];
    #pragma unroll
    for (int jx = 0; jx < 8; ++jx) {
        float M = m[0][jx];
        #pragma unroll
        for (int s = 1; s < SPLIT; ++s) M = fmaxf(M, m[s][jx]);
        float L = 0.f;
        #pragma unroll
        for (int s = 0; s < SPLIT; ++s) {
            float ws = l[s][jx] * __builtin_amdgcn_exp2f(m[s][jx] - M);
            w[s][jx] = ws; L += ws;
        }
        float invL = 1.f / L;
        #pragma unroll
        for (int s = 0; s < SPLIT; ++s) w[s][jx] *= invL;
    }

    float o[8];
    #pragma unroll
    for (int jx = 0; jx < 8; ++jx) o[jx] = 0.f;
    #pragma unroll
    for (int s = 0; s < SPLIT; ++s) {
        half8 h = *(const half8*)&Opart[((size_t)(s * Bb + b) * Dd + d) * Nn + n0];
        #pragma unroll
        for (int jx = 0; jx < 8; ++jx) o[jx] += w[s][jx] * (float)h[jx];
    }
    float* op = out + ((size_t)b * Dd + d) * Nn + n0;
    f32x4 o0 = {o[0], o[1], o[2], o[3]};
    f32x4 o1 = {o[4], o[5], o[6], o[7]};
    *(f32x4*)op = o0;
    *(f32x4*)(op + 4) = o1;
}

extern "C" void kernel_launch(void* const* d_in, const int* in_sizes, int n_in,
                              void* d_out, int out_size, void* d_ws, size_t ws_size,
                              hipStream_t stream) {
    const float* x  = (const float*)d_in[0];
    const float* Wq = (const float*)d_in[1];
    const float* bq = (const float*)d_in[2];
    const float* Wk = (const float*)d_in[3];
    const float* bk = (const float*)d_in[4];
    const float* Wv = (const float*)d_in[5];
    const float* bv = (const float*)d_in[6];
    float* out = (float*)d_out;

    f16* Qh    = (f16*)d_ws;
    f16* Kh    = Qh + (size_t)Bb * Nn * Dd;
    f16* Vth   = Kh + (size_t)Bb * Nn * Dd;
    f16* Wt    = Vth + (size_t)Bb * Nn * Dd;
    f16* Opart = Wt + (size_t)3 * Dd * Dd;
    float* mpart = (float*)(Opart + (size_t)SPLIT * Bb * Dd * Nn);
    float* lpart = mpart + (size_t)SPLIT * Bb * Nn;

    wtrans<<<dim3(16, 3), 256, 0, stream>>>(Wq, Wk, Wv, Wt);
    qkv_fused<<<dim3(Nn / 64, 2, Bb), 256, 0, stream>>>(
        x, Wt, bq, bk, bv, Qh, Kh, Vth);
    attn_mfma<<<dim3(Nn / BQ * Bb * SPLIT), 512, 0, stream>>>(
        Qh, Kh, Vth, Opart, mpart, lpart);
    combine<<<dim3(Nn / 2048, Dd, Bb), 256, 0, stream>>>(
        Opart, mpart, lpart, out);
}

// Round 10
// 204.367 us; speedup vs baseline: 2.1079x; 1.0234x over previous
//
#include <hip/hip_runtime.h>
#include <math.h>

#define Dd 256
#define Nn 4096
#define Bb 4
#define BQ 128      // q rows per attn block (8 waves x 16 in S phase)
#define BK 128      // kv rows per tile
#define SPLIT 2     // KV splits -> grid exactly 256 blocks = 1 round

typedef _Float16 f16;
typedef _Float16 half8 __attribute__((ext_vector_type(8)));
typedef _Float16 half4 __attribute__((ext_vector_type(4)));
typedef float f32x4 __attribute__((ext_vector_type(4)));

#define LOG2E 1.4426950408889634f

// DPP row_ror butterfly over 16-lane rows (VALU pipe, not LDS)
template <int CTRL>
__device__ __forceinline__ float dppf(float x) {
    int r = __builtin_amdgcn_update_dpp(0, __builtin_bit_cast(int, x),
                                        CTRL, 0xF, 0xF, false);
    return __builtin_bit_cast(float, r);
}
__device__ __forceinline__ float red16_max(float x) {
    x = fmaxf(x, dppf<0x128>(x));
    x = fmaxf(x, dppf<0x124>(x));
    x = fmaxf(x, dppf<0x122>(x));
    x = fmaxf(x, dppf<0x121>(x));
    return x;
}
__device__ __forceinline__ float red16_sum(float x) {
    x += dppf<0x128>(x); x += dppf<0x124>(x);
    x += dppf<0x122>(x); x += dppf<0x121>(x);
    return x;
}

// ---------------------------------------------------------------------------
// Kernel 0: W transpose+cast.  Wt[which][d'][d] = (f16) W[d][d']
// ---------------------------------------------------------------------------
__global__ __launch_bounds__(256) void wtrans(
    const float* __restrict__ Wq, const float* __restrict__ Wk,
    const float* __restrict__ Wv, f16* __restrict__ Wt)
{
    __shared__ float ld[64][65];
    const int which = blockIdx.y;
    const float* W = which == 0 ? Wq : (which == 1 ? Wk : Wv);
    const int tr = (blockIdx.x >> 2) * 64;
    const int tc = (blockIdx.x & 3) * 64;
    const int t = threadIdx.x;
    #pragma unroll
    for (int i = 0; i < 16; ++i) {
        int u = t + i * 256, r = u >> 6, c = u & 63;
        ld[r][c] = W[(size_t)(tr + r) * Dd + tc + c];
    }
    __syncthreads();
    f16* Wo = Wt + (size_t)which * Dd * Dd;
    #pragma unroll
    for (int i = 0; i < 16; ++i) {
        int u = t + i * 256, cp = u >> 6, rp = u & 63;
        Wo[(size_t)(tc + cp) * Dd + tr + rp] = (f16)ld[rp][cp];
    }
}

// ---------------------------------------------------------------------------
// Kernel 1: QKV projection (exact R5 winner): W fragments in registers from
// f16 Wt (b128 loads), xT staged once, 1 barrier, 256-thr blocks, 2/CU.
// ---------------------------------------------------------------------------
__global__ __launch_bounds__(256) void qkv_fused(
    const float* __restrict__ x, const f16* __restrict__ Wt,
    const float* __restrict__ bq, const float* __restrict__ bk,
    const float* __restrict__ bv,
    f16* __restrict__ Qh, f16* __restrict__ Kh, f16* __restrict__ Vth)
{
    __shared__ __align__(16) f16 xT[64][264];   // 33792 B

    const int t = threadIdx.x;
    const int wave = t >> 6, lane = t & 63, quad = lane >> 4, l15 = lane & 15;
    const int n0  = blockIdx.x * 64;
    const int ch  = blockIdx.y;           // col half: [128*ch, 128*ch+128)
    const int b   = blockIdx.z;
    const int col0 = ch * 128 + wave * 32;  // this wave's 32 out-cols

    // Stage xT[n][d] = (f16) x[b][d][n0+n]; 256 threads x 16 float4 reads
    const float* xb = x + (size_t)b * Dd * Nn;
    #pragma unroll
    for (int i = 0; i < 16; ++i) {
        int u = t + i * 256, d = u >> 4, nq = (u & 15) * 4;
        float4 v4 = *(const float4*)&xb[(size_t)d * Nn + n0 + nq];
        xT[nq + 0][d] = (f16)v4.x; xT[nq + 1][d] = (f16)v4.y;
        xT[nq + 2][d] = (f16)v4.z; xT[nq + 3][d] = (f16)v4.w;
    }

    // Biases for this wave's two col-tiles (direct, no LDS)
    float bias[3][2];
    #pragma unroll
    for (int ct = 0; ct < 2; ++ct) {
        int col = col0 + ct * 16 + l15;
        bias[0][ct] = bq[col]; bias[1][ct] = bk[col]; bias[2][ct] = bv[col];
    }

    __syncthreads();   // the ONLY barrier: xT visible, read-only hereafter

    #pragma unroll
    for (int which = 0; which < 3; ++which) {
        // B-fragments from L2: 16 x b128 per wave, register-resident
        const f16* Wb = Wt + (size_t)which * Dd * Dd;
        half8 wf[2][8];
        #pragma unroll
        for (int ct = 0; ct < 2; ++ct)
            #pragma unroll
            for (int c = 0; c < 8; ++c)
                wf[ct][c] = *(const half8*)(Wb
                    + (size_t)(col0 + ct * 16 + l15) * Dd + c * 32 + quad * 8);

        // 64 rows x 32 cols per wave: 4 row-groups x 2 col-tiles x 8 chunks
        f32x4 acc[4][2];
        #pragma unroll
        for (int rg = 0; rg < 4; ++rg) {
            acc[rg][0] = (f32x4){0.f, 0.f, 0.f, 0.f};
            acc[rg][1] = (f32x4){0.f, 0.f, 0.f, 0.f};
        }
        #pragma unroll
        for (int rg = 0; rg < 4; ++rg) {
            #pragma unroll
            for (int c = 0; c < 8; ++c) {
                half8 a = *(const half8*)&xT[rg * 16 + l15][c * 32 + quad * 8];
                acc[rg][0] = __builtin_amdgcn_mfma_f32_16x16x32_f16(
                    a, wf[0][c], acc[rg][0], 0, 0, 0);
                acc[rg][1] = __builtin_amdgcn_mfma_f32_16x16x32_f16(
                    a, wf[1][c], acc[rg][1], 0, 0, 0);
            }
        }

        // Epilogue
        if (which < 2) {
            f16* O = (which == 0 ? Qh : Kh) + ((size_t)b * Nn + n0) * Dd;
            #pragma unroll
            for (int rg = 0; rg < 4; ++rg) {
                #pragma unroll
                for (int ct = 0; ct < 2; ++ct) {
                    int col = col0 + ct * 16 + l15;
                    float bvv = bias[which][ct];
                    #pragma unroll
                    for (int r = 0; r < 4; ++r)
                        O[(size_t)(rg * 16 + quad * 4 + r) * Dd + col] =
                            (f16)(acc[rg][ct][r] + bvv);
                }
            }
        } else {
            f16* O = Vth + (size_t)b * Dd * Nn;
            #pragma unroll
            for (int rg = 0; rg < 4; ++rg) {
                #pragma unroll
                for (int ct = 0; ct < 2; ++ct) {
                    int col = col0 + ct * 16 + l15;
                    float bvv = bias[2][ct];
                    half4 o;
                    #pragma unroll
                    for (int r = 0; r < 4; ++r) o[r] = (f16)(acc[rg][ct][r] + bvv);
                    *(half4*)&O[(size_t)col * Nn + n0 + rg * 16 + quad * 4] = o;
                }
            }
        }
    }
}

// ---------------------------------------------------------------------------
// Kernel 2: MFMA flash attention = R9 (T14 + K dbuf + XCD swizzle; the
// swizzle cut FETCH 69.7->16.5 MB, K/V now L2-resident) + ONE change:
// barrier D ELIMINATED (3 -> 2 barriers/tile). The K(k+1) commit moves into
// the publish section: at tile k, Ks[buf^1] was last read by tile k-1's PV,
// and THIS tile's barrier B2 already synchronizes after that point, so the
// write is safe there; barrier C then makes it visible for the next tile's
// S phase. kreg loads (issued at tile top) have S+softmax (~2-3K cy) to
// land before the ds_write -- ample for L2 hits. kreg lifetime SHRINKS
// (top->publish vs top->post-PV). Removes 16 full vmcnt/lgkm drains.
// ---------------------------------------------------------------------------
__global__ __launch_bounds__(512, 2) void attn_mfma(
    const f16* __restrict__ Qh, const f16* __restrict__ Kh,
    const f16* __restrict__ Vth, f16* __restrict__ Opart,
    float* __restrict__ mpart, float* __restrict__ lpart)
{
    __shared__ __align__(16) f16 Ks[2][BK][264];  // 135168 B, double-buffered
    __shared__ float alpha_s[8][16];              //   512 B
    __shared__ float l_sh[8][16];                 //   512 B

    const int t    = threadIdx.x;
    const int wave = t >> 6, lane = t & 63;
    const int quad = lane >> 4, l15 = lane & 15;
    const int bid  = blockIdx.x;
    const int pair = bid & 7;              // -> XCD bid%8
    const int b    = pair & 3;
    const int s    = pair >> 2;
    const int q0   = (bid >> 3) * BQ;
    const int qw   = q0 + wave * 16;       // this wave's S-phase q rows
    const int kvlen = Nn / SPLIT;
    const int kv0  = s * kvlen;

    // Q A-fragments, pre-scaled by log2(e)
    half8 qf[8];
    const f16* Qrow = Qh + ((size_t)b * Nn + qw + l15) * Dd + quad * 8;
    #pragma unroll
    for (int c = 0; c < 8; ++c) {
        qf[c] = *(const half8*)(Qrow + c * 32);
        qf[c] = qf[c] * (f16)LOG2E;
    }

    // acc[qb*2+dt]: q-block qb (0..7), d-cols 32*wave + dt*16 + l15 (dt 0..1)
    f32x4 acc[16];
    #pragma unroll
    for (int n = 0; n < 16; ++n) acc[n] = (f32x4){0.f, 0.f, 0.f, 0.f};
    f32x4 m4 = {-1e30f, -1e30f, -1e30f, -1e30f};
    f32x4 l4 = {0.f, 0.f, 0.f, 0.f};

    const f16* Kb   = Kh + (size_t)b * Nn * Dd;
    const f16* Vrow = Vth + (size_t)b * Dd * Nn
                    + (size_t)(wave * 32 + l15) * Nn + quad * 8;

    // Prologue: stage first K tile into Ks[0] (exposed once per block)
    #pragma unroll
    for (int i = 0; i < 8; ++i) {
        int u = t + i * 512;
        int r = u >> 5, c = u & 31;
        *(half8*)&Ks[0][r][c * 8] =
            *(const half8*)(Kb + (size_t)(kv0 + r) * Dd + c * 8);
    }
    __syncthreads();

    int buf = 0;
    for (int k0 = kv0; k0 < kv0 + kvlen; k0 += BK) {
        // T14 issue-early: next K tile global loads -> registers. Committed
        // to LDS at the publish point (post-B2), ~S+softmax later.
        const int kn = k0 + BK;
        const bool havenext = kn < kv0 + kvlen;   // block-uniform
        half8 kreg[8];
        if (havenext) {
            #pragma unroll
            for (int i = 0; i < 8; ++i) {
                int u = t + i * 512;
                int r = u >> 5, c = u & 31;
                kreg[i] = *(const half8*)(Kb + (size_t)(kn + r) * Dd + c * 8);
            }
        }

        // V loads for THIS tile: 2 d-tiles x 4 kv-quarters; consumed in PV
        half8 vbf[2][4];
        #pragma unroll
        for (int dt = 0; dt < 2; ++dt) {
            #pragma unroll
            for (int cbb = 0; cbb < 4; ++cbb)
                vbf[dt][cbb] = *(const half8*)(Vrow + (size_t)dt * 16 * Nn + k0 + cbb * 32);
        }

        // S = Q K^T (log2 domain) from Ks[buf], eight 16x16 col-blocks
        f32x4 S[8];
        #pragma unroll
        for (int cb = 0; cb < 8; ++cb) S[cb] = (f32x4){0.f, 0.f, 0.f, 0.f};
        #pragma unroll
        for (int c = 0; c < 8; ++c) {
            #pragma unroll
            for (int cb = 0; cb < 8; ++cb) {
                half8 kb = *(const half8*)&Ks[buf][cb * 16 + l15][c * 32 + quad * 8];
                S[cb] = __builtin_amdgcn_mfma_f32_16x16x32_f16(qf[c], kb, S[cb], 0, 0, 0);
            }
        }

        // Online softmax (exp2 domain), DPP reductions; P computed in-place
        f32x4 tmax = S[0];
        #pragma unroll
        for (int cb = 1; cb < 8; ++cb) {
            tmax.x = fmaxf(tmax.x, S[cb].x); tmax.y = fmaxf(tmax.y, S[cb].y);
            tmax.z = fmaxf(tmax.z, S[cb].z); tmax.w = fmaxf(tmax.w, S[cb].w);
        }
        tmax.x = red16_max(tmax.x); tmax.y = red16_max(tmax.y);
        tmax.z = red16_max(tmax.z); tmax.w = red16_max(tmax.w);
        f32x4 newm;
        newm.x = fmaxf(m4.x, tmax.x); newm.y = fmaxf(m4.y, tmax.y);
        newm.z = fmaxf(m4.z, tmax.z); newm.w = fmaxf(m4.w, tmax.w);
        f32x4 al;
        al.x = __builtin_amdgcn_exp2f(m4.x - newm.x);
        al.y = __builtin_amdgcn_exp2f(m4.y - newm.y);
        al.z = __builtin_amdgcn_exp2f(m4.z - newm.z);
        al.w = __builtin_amdgcn_exp2f(m4.w - newm.w);
        #pragma unroll
        for (int cb = 0; cb < 8; ++cb) {       // P overwrites S (reg saver)
            S[cb].x = __builtin_amdgcn_exp2f(S[cb].x - newm.x);
            S[cb].y = __builtin_amdgcn_exp2f(S[cb].y - newm.y);
            S[cb].z = __builtin_amdgcn_exp2f(S[cb].z - newm.z);
            S[cb].w = __builtin_amdgcn_exp2f(S[cb].w - newm.w);
        }
        f32x4 rsum = S[0];
        #pragma unroll
        for (int cb = 1; cb < 8; ++cb) rsum += S[cb];
        rsum.x = red16_sum(rsum.x); rsum.y = red16_sum(rsum.y);
        rsum.z = red16_sum(rsum.z); rsum.w = red16_sum(rsum.w);
        l4 = l4 * al + rsum;
        m4 = newm;

        __syncthreads();   // B2: all waves' S reads of Ks[buf] done AND all
                           // waves' prior-tile PV reads of Ks[buf^1] done.

        // Publish P (f16) + alpha into the alias of Ks[buf] (K tile dead),
        // and commit prefetched K(k+1) into Ks[buf^1] (dead since B2).
        f16 (*Ps)[16][136] = (f16 (*)[16][136])&Ks[buf][0][0];
        const int pr = quad * 4;
        #pragma unroll
        for (int cb = 0; cb < 8; ++cb) {
            Ps[wave][pr + 0][cb * 16 + l15] = (f16)S[cb].x;
            Ps[wave][pr + 1][cb * 16 + l15] = (f16)S[cb].y;
            Ps[wave][pr + 2][cb * 16 + l15] = (f16)S[cb].z;
            Ps[wave][pr + 3][cb * 16 + l15] = (f16)S[cb].w;
        }
        if (l15 == 0) {
            float4 a4 = {al.x, al.y, al.z, al.w};
            *(float4*)&alpha_s[wave][pr] = a4;
        }
        if (havenext) {
            #pragma unroll
            for (int i = 0; i < 8; ++i) {
                int u = t + i * 512;
                int r = u >> 5, c = u & 31;
                *(half8*)&Ks[buf ^ 1][r][c * 8] = kreg[i];
            }
        }
        __syncthreads();   // C: Ps/alpha AND K(k+1) visible

        // Rescale O by each q-block's alpha (skip when converged)
        float4 alq[8];
        int need = 0;
        #pragma unroll
        for (int qb = 0; qb < 8; ++qb) {
            alq[qb] = *(const float4*)&alpha_s[qb][pr];
            need |= (alq[qb].x != 1.f) | (alq[qb].y != 1.f) |
                    (alq[qb].z != 1.f) | (alq[qb].w != 1.f);
        }
        if (__any(need)) {
            #pragma unroll
            for (int qb = 0; qb < 8; ++qb) {
                f32x4 a = {alq[qb].x, alq[qb].y, alq[qb].z, alq[qb].w};
                acc[qb * 2 + 0] *= a;
                acc[qb * 2 + 1] *= a;
            }
        }

        // PV: 8 q-blocks x 2 d-tiles x 4 kv-quarters; A-frag one b128 each
        #pragma unroll
        for (int qb = 0; qb < 8; ++qb) {
            #pragma unroll
            for (int cbb = 0; cbb < 4; ++cbb) {
                half8 ap = *(const half8*)&Ps[qb][l15][cbb * 32 + quad * 8];
                acc[qb * 2 + 0] = __builtin_amdgcn_mfma_f32_16x16x32_f16(
                    ap, vbf[0][cbb], acc[qb * 2 + 0], 0, 0, 0);
                acc[qb * 2 + 1] = __builtin_amdgcn_mfma_f32_16x16x32_f16(
                    ap, vbf[1][cbb], acc[qb * 2 + 1], 0, 0, 0);
            }
        }

        if (havenext) buf ^= 1;
        // (no barrier D: next tile's B2 provides the needed sync)
    }

    // Publish l, write m/l partials (this wave's own 16 q rows)
    if (l15 == 0) {
        const int pr = quad * 4;
        float4 lv = {l4.x, l4.y, l4.z, l4.w};
        *(float4*)&l_sh[wave][pr] = lv;
        float mv[4] = {m4.x, m4.y, m4.z, m4.w};
        float lvv[4] = {l4.x, l4.y, l4.z, l4.w};
        #pragma unroll
        for (int r = 0; r < 4; ++r) {
            int n = qw + pr + r;
            mpart[(size_t)(s * Bb + b) * Nn + n] = mv[r];
            lpart[(size_t)(s * Bb + b) * Nn + n] = lvv[r];
        }
    }
    __syncthreads();

    // Normalize + store partial O: 8 q-blocks x this wave's 2 d-tiles
    f16* Ob = Opart + (size_t)(s * Bb + b) * Dd * Nn;
    #pragma unroll
    for (int qb = 0; qb < 8; ++qb) {
        float4 lq = *(const float4*)&l_sh[qb][quad * 4];
        f32x4 inv = {1.f / lq.x, 1.f / lq.y, 1.f / lq.z, 1.f / lq.w};
        #pragma unroll
        for (int dt = 0; dt < 2; ++dt) {
            int d = wave * 32 + dt * 16 + l15;
            f32x4 o = acc[qb * 2 + dt] * inv;
            half4 oh;
            oh[0] = (f16)o.x; oh[1] = (f16)o.y; oh[2] = (f16)o.z; oh[3] = (f16)o.w;
            *(half4*)&Ob[(size_t)d * Nn + q0 + qb * 16 + quad * 4] = oh;
        }
    }
}

// ---------------------------------------------------------------------------
// Kernel 3: combine split partials (exp2 domain).
// ---------------------------------------------------------------------------
__global__ __launch_bounds__(256) void combine(
    const f16* __restrict__ Opart, const float* __restrict__ mpart,
    const float* __restrict__ lpart, float* __restrict__ out)
{
    const int t = threadIdx.x;
    const int n0 = (blockIdx.x * 256 + t) * 8;
    const int d = blockIdx.y, b = blockIdx.z;

    float m[SPLIT][8], l[SPLIT][8];
    #pragma unroll
    for (int s = 0; s < SPLIT; ++s) {
        size_t base = (size_t)(s * Bb + b) * Nn + n0;
        float4 a0 = *(const float4*)&mpart[base];
        float4 a1 = *(const float4*)&mpart[base + 4];
        float4 c0 = *(const float4*)&lpart[base];
        float4 c1 = *(const float4*)&lpart[base + 4];
        m[s][0]=a0.x; m[s][1]=a0.y; m[s][2]=a0.z; m[s][3]=a0.w;
        m[s][4]=a1.x; m[s][5]=a1.y; m[s][6]=a1.z; m[s][7]=a1.w;
        l[s][0]=c0.x; l[s][1]=c0.y; l[s][2]=c0.z; l[s][3]=c0.w;
        l[s][4]=c1.x; l[s][5]=c1.y; l[s][6]=c1.z; l[s][7]=c1.w;
    }
    float w[SPLIT][8];
    #pragma unroll
    for (int jx = 0; jx < 8; ++jx) {
        float M = m[0][jx];
        #pragma unroll
        for (int s = 1; s < SPLIT; ++s) M = fmaxf(M, m[s][jx]);
        float L = 0.f;
        #pragma unroll
        for (int s = 0; s < SPLIT; ++s) {
            float ws = l[s][jx] * __builtin_amdgcn_exp2f(m[s][jx] - M);
            w[s][jx] = ws; L += ws;
        }
        float invL = 1.f / L;
        #pragma unroll
        for (int s = 0; s < SPLIT; ++s) w[s][jx] *= invL;
    }

    float o[8];
    #pragma unroll
    for (int jx = 0; jx < 8; ++jx) o[jx] = 0.f;
    #pragma unroll
    for (int s = 0; s < SPLIT; ++s) {
        half8 h = *(const half8*)&Opart[((size_t)(s * Bb + b) * Dd + d) * Nn + n0];
        #pragma unroll
        for (int jx = 0; jx < 8; ++jx) o[jx] += w[s][jx] * (float)h[jx];
    }
    float* op = out + ((size_t)b * Dd + d) * Nn + n0;
    f32x4 o0 = {o[0], o[1], o[2], o[3]};
    f32x4 o1 = {o[4], o[5], o[6], o[7]};
    *(f32x4*)op = o0;
    *(f32x4*)(op + 4) = o1;
}

extern "C" void kernel_launch(void* const* d_in, const int* in_sizes, int n_in,
                              void* d_out, int out_size, void* d_ws, size_t ws_size,
                              hipStream_t stream) {
    const float* x  = (const float*)d_in[0];
    const float* Wq = (const float*)d_in[1];
    const float* bq = (const float*)d_in[2];
    const float* Wk = (const float*)d_in[3];
    const float* bk = (const float*)d_in[4];
    const float* Wv = (const float*)d_in[5];
    const float* bv = (const float*)d_in[6];
    float* out = (float*)d_out;

    f16* Qh    = (f16*)d_ws;
    f16* Kh    = Qh + (size_t)Bb * Nn * Dd;
    f16* Vth   = Kh + (size_t)Bb * Nn * Dd;
    f16* Wt    = Vth + (size_t)Bb * Nn * Dd;
    f16* Opart = Wt + (size_t)3 * Dd * Dd;
    float* mpart = (float*)(Opart + (size_t)SPLIT * Bb * Dd * Nn);
    float* lpart = mpart + (size_t)SPLIT * Bb * Nn;

    wtrans<<<dim3(16, 3), 256, 0, stream>>>(Wq, Wk, Wv, Wt);
    qkv_fused<<<dim3(Nn / 64, 2, Bb), 256, 0, stream>>>(
        x, Wt, bq, bk, bv, Qh, Kh, Vth);
    attn_mfma<<<dim3(Nn / BQ * Bb * SPLIT), 512, 0, stream>>>(
        Qh, Kh, Vth, Opart, mpart, lpart);
    combine<<<dim3(Nn / 2048, Dd, Bb), 256, 0, stream>>>(
        Opart, mpart, lpart, out);
}